// Round 1
// baseline (290.836 us; speedup 1.0000x reference)
//
#include <hip/hip_runtime.h>
#include <hip/hip_bf16.h>
#include <cstdint>

#define B 32
#define D 8732
#define C 21
#define L 32
#define O 8
#define BD (B*D)
#define NCH ((BD + 1023) / 1024)   // 273 chunks of 1024

struct Accum {
  double loss_l, loss_p, ce_pos, ce_neg, desk, trip_sum, trip_cnt;
  unsigned long long n_pp, n_np;
  int num_pos[B];
  int total_pos;
  int Pc;
};

__device__ inline double blockReduceSumD(double v, double* sbuf) {
  int tid = threadIdx.x;
  sbuf[tid] = v; __syncthreads();
  for (int s = blockDim.x / 2; s > 0; s >>= 1) {
    if (tid < s) sbuf[tid] += sbuf[tid + s];
    __syncthreads();
  }
  double r = sbuf[0]; __syncthreads();
  return r;
}

// ---------- K1: matching (one block per batch) ----------
__global__ void k_match(const float* __restrict__ dbox, const float* __restrict__ targets,
                        float* __restrict__ bt_ov, int* __restrict__ bt_idx) {
  int b = blockIdx.x;
  int tid = threadIdx.x;
  __shared__ float tb[O][4];
  __shared__ float ta[O];
  __shared__ float sv[256];
  __shared__ int   si[256];
  __shared__ int   bp[O];
  if (tid < O) {
    const float* tr = targets + ((size_t)b * O + tid) * 9;
    tb[tid][0] = tr[0]; tb[tid][1] = tr[1]; tb[tid][2] = tr[2]; tb[tid][3] = tr[3];
    ta[tid] = (tr[2] - tr[0]) * (tr[3] - tr[1]);
  }
  __syncthreads();
  float pv[O]; int pi[O];
  #pragma unroll
  for (int t = 0; t < O; t++) { pv[t] = -1.0f; pi[t] = 0; }
  for (int d = tid; d < D; d += blockDim.x) {
    float cx = dbox[d*4+0], cy = dbox[d*4+1], w = dbox[d*4+2], h = dbox[d*4+3];
    float px1 = cx - 0.5f*w, py1 = cy - 0.5f*h, px2 = cx + 0.5f*w, py2 = cy + 0.5f*h;
    float areaB = w * h;
    float bv = -1.0f; int bi = 0;
    #pragma unroll
    for (int t = 0; t < O; t++) {
      float lx = fmaxf(tb[t][0], px1), ly = fmaxf(tb[t][1], py1);
      float rx = fminf(tb[t][2], px2), ry = fminf(tb[t][3], py2);
      float iw = fmaxf(rx - lx, 0.f), ih = fmaxf(ry - ly, 0.f);
      float inter = iw * ih;
      float iou = inter / (ta[t] + areaB - inter);
      if (iou > bv) { bv = iou; bi = t; }                 // argmax axis=0: first max wins
      if (iou > pv[t]) { pv[t] = iou; pi[t] = d; }        // argmax axis=1 per truth
    }
    bt_ov[(size_t)b*D + d] = bv;
    bt_idx[(size_t)b*D + d] = bi;
  }
  // reduce best prior per truth (tie-break: smaller index)
  for (int t = 0; t < O; t++) {
    sv[tid] = pv[t]; si[tid] = pi[t];
    __syncthreads();
    for (int s = blockDim.x / 2; s > 0; s >>= 1) {
      if (tid < s) {
        if (sv[tid+s] > sv[tid] || (sv[tid+s] == sv[tid] && si[tid+s] < si[tid])) {
          sv[tid] = sv[tid+s]; si[tid] = si[tid+s];
        }
      }
      __syncthreads();
    }
    if (tid == 0) bp[t] = si[0];
    __syncthreads();
  }
  if (tid == 0) {
    // sequential overrides: numpy scatter semantics (last truth wins on dup)
    for (int t = 0; t < O; t++) {
      int dd = bp[t];
      bt_ov[(size_t)b*D + dd] = 2.0f;
      bt_idx[(size_t)b*D + dd] = t;
    }
  }
}

// ---------- K2: conf_t, ce, loc/pose losses ----------
__global__ void k_losses(const float* __restrict__ loc, const float* __restrict__ conf,
                         const float* __restrict__ pose, const float* __restrict__ dbox,
                         const float* __restrict__ targets, const float* __restrict__ bt_ov,
                         const int* __restrict__ bt_idx, int* __restrict__ conf_t,
                         float* __restrict__ ce_mined, Accum* acc) {
  __shared__ double sbuf[256];
  int b = blockIdx.y;
  int d = blockIdx.x * 256 + threadIdx.x;
  double ll = 0, lp = 0, cp = 0; int np = 0;
  if (d < D) {
    size_t bd = (size_t)b * D + d;
    int j = bt_idx[bd];
    float ov = bt_ov[bd];
    const float* tr = targets + ((size_t)b * O + j) * 9;
    int cls = (ov < 0.5f) ? 0 : ((int)tr[4] + 1);
    conf_t[bd] = cls;
    const float* x = conf + bd * C;
    float m = x[0];
    #pragma unroll
    for (int c = 1; c < C; c++) m = fmaxf(m, x[c]);
    float s = 0.f;
    #pragma unroll
    for (int c = 0; c < C; c++) s += expf(x[c] - m);
    float ce = m + logf(s) - x[cls];
    if (cls > 0) {
      np = 1; cp = ce;
      ce_mined[bd] = 0.f;
      float wp = dbox[d*4+2], hp = dbox[d*4+3];
      float g0 = ((tr[0] + tr[2]) * 0.5f - dbox[d*4+0]) / (0.1f * wp);
      float g1 = ((tr[1] + tr[3]) * 0.5f - dbox[d*4+1]) / (0.1f * hp);
      float g2 = logf((tr[2] - tr[0]) / wp) / 0.2f;
      float g3 = logf((tr[3] - tr[1]) / hp) / 0.2f;
      float g[4] = {g0, g1, g2, g3};
      const float* lo = loc + bd * 4;
      #pragma unroll
      for (int q = 0; q < 4; q++) {
        float dv = lo[q] - g[q];
        float a = fabsf(dv);
        ll += (double)((a < 1.f) ? (0.5f * dv * dv) : (a - 0.5f));
      }
      const float* po = pose + bd * 3;
      #pragma unroll
      for (int q = 0; q < 3; q++) {
        float dv = po[q] - tr[5 + q];
        lp += (double)dv * (double)dv;
      }
    } else {
      ce_mined[bd] = fmaxf(ce, 0.f);
    }
  }
  double tll = blockReduceSumD(ll, sbuf);
  double tlp = blockReduceSumD(lp, sbuf);
  double tcp = blockReduceSumD(cp, sbuf);
  double tnp = blockReduceSumD((double)np, sbuf);
  if (threadIdx.x == 0) {
    if (tll != 0.0) atomicAdd(&acc->loss_l, tll);
    if (tlp != 0.0) atomicAdd(&acc->loss_p, tlp);
    if (tcp != 0.0) atomicAdd(&acc->ce_pos, tcp);
    int inp = (int)(tnp + 0.5);
    if (inp) { atomicAdd(&acc->num_pos[b], inp); atomicAdd(&acc->total_pos, inp); }
  }
}

// ---------- K3: per-batch top-k negative CE sum (radix select) ----------
__global__ void k_topk(const float* __restrict__ ce_mined, Accum* acc) {
  int b = blockIdx.x;
  int tid = threadIdx.x;
  __shared__ int hist[256];
  __shared__ unsigned int sh_prefix;
  __shared__ int sh_k;
  __shared__ double sbuf[256];
  int k = acc->num_pos[b] * 3;
  if (k > D) k = D;
  const float* ce = ce_mined + (size_t)b * D;
  unsigned int prefix = 0; int kk = k;
  for (int pass = 0; pass < 4; pass++) {
    int shift = 24 - 8 * pass;
    hist[tid] = 0;
    __syncthreads();
    unsigned int himask = (pass == 0) ? 0u : (0xFFFFFFFFu << (shift + 8));
    for (int d = tid; d < D; d += 256) {
      unsigned int key = __float_as_uint(ce[d]);
      if ((key & himask) == (prefix & himask))
        atomicAdd(&hist[(key >> shift) & 255], 1);
    }
    __syncthreads();
    if (tid == 0) {
      int cum = 0, digit = 0;
      for (int bin = 255; bin >= 0; bin--) {
        int h = hist[bin];
        if (cum + h >= kk) { digit = bin; break; }
        cum += h;
      }
      sh_k = kk - cum;
      sh_prefix = prefix | ((unsigned)digit << shift);
    }
    __syncthreads();
    prefix = sh_prefix; kk = sh_k;
    __syncthreads();
  }
  float T = __uint_as_float(prefix);
  double sgt = 0; int cgt = 0;
  for (int d = tid; d < D; d += 256) {
    float v = ce[d];
    if (__float_as_uint(v) > prefix) { sgt += (double)v; cgt++; }
  }
  double tsg = blockReduceSumD(sgt, sbuf);
  double tcg = blockReduceSumD((double)cgt, sbuf);
  if (tid == 0) {
    double S = tsg + ((double)k - tcg) * (double)T;
    atomicAdd(&acc->ce_neg, S);
  }
}

// ---------- K4: stable selection of first 256 pos / neg flat indices ----------
__global__ void k_selcount(const int* __restrict__ conf_t, int* __restrict__ posCnt,
                           int* __restrict__ negCnt) {
  int i = blockIdx.x * 1024 + threadIdx.x;
  int p = (i < BD) && (conf_t[i] > 0);
  int n = (i < BD) && !p && (i < BD);
  n = (i < BD) && (conf_t[i] == 0);
  __shared__ int sp, sn;
  if (threadIdx.x == 0) { sp = 0; sn = 0; }
  __syncthreads();
  unsigned long long pm = __ballot(p), nm = __ballot(n);
  if ((threadIdx.x & 63) == 0) { atomicAdd(&sp, __popcll(pm)); atomicAdd(&sn, __popcll(nm)); }
  __syncthreads();
  if (threadIdx.x == 0) { posCnt[blockIdx.x] = sp; negCnt[blockIdx.x] = sn; }
}

__global__ void k_selscan(const int* __restrict__ posCnt, const int* __restrict__ negCnt,
                          int* __restrict__ posBase, int* __restrict__ negBase, Accum* acc) {
  __shared__ int sp[NCH], sn[NCH];
  for (int c = threadIdx.x; c < NCH; c += blockDim.x) { sp[c] = posCnt[c]; sn[c] = negCnt[c]; }
  __syncthreads();
  if (threadIdx.x == 0) {
    int p = 0, n = 0;
    for (int c = 0; c < NCH; c++) {
      int tp = sp[c], tn = sn[c];
      sp[c] = p; sn[c] = n;
      p += tp; n += tn;
    }
    acc->Pc = (p < 256) ? p : 256;
  }
  __syncthreads();
  for (int c = threadIdx.x; c < NCH; c += blockDim.x) { posBase[c] = sp[c]; negBase[c] = sn[c]; }
}

__global__ void k_selwrite(const int* __restrict__ conf_t, const int* __restrict__ posBase,
                           const int* __restrict__ negBase, int* __restrict__ posIdx,
                           int* __restrict__ negIdx) {
  int ch = blockIdx.x;
  int pbase = posBase[ch], nbase = negBase[ch];
  if (pbase >= 256 && nbase >= 256) return;
  int i = ch * 1024 + threadIdx.x;
  int p = (i < BD) && (conf_t[i] > 0);
  int n = (i < BD) && (conf_t[i] == 0);
  unsigned long long pm = __ballot(p), nm = __ballot(n);
  int lane = threadIdx.x & 63, wave = threadIdx.x >> 6;
  __shared__ int wp[16], wn[16];
  if (lane == 0) { wp[wave] = __popcll(pm); wn[wave] = __popcll(nm); }
  __syncthreads();
  int pb = pbase, nb = nbase;
  for (int w = 0; w < wave; w++) { pb += wp[w]; nb += wn[w]; }
  unsigned long long lt = (lane == 0) ? 0ull : (~0ull >> (64 - lane));
  int prank = pb + __popcll(pm & lt);
  int nrank = nb + __popcll(nm & lt);
  if (p && prank < 256) posIdx[prank] = i;
  if (n && nrank < 256) negIdx[nrank] = i;
}

// ---------- K5a: gather embeddings / labels / poses ----------
__global__ void k_gather(const float* __restrict__ line, const float* __restrict__ targets,
                         const int* __restrict__ conf_t, const int* __restrict__ bt_idx,
                         const int* __restrict__ posIdx, const int* __restrict__ negIdx,
                         const Accum* acc, float* __restrict__ emb, float* __restrict__ nemb,
                         float* __restrict__ qp, int* __restrict__ lab) {
  int g = threadIdx.x;
  int Pc = acc->Pc;
  int flat = (g < Pc) ? posIdx[g] : negIdx[g - Pc];
  int b = flat / D, j = bt_idx[flat];
  const float* e = line + (size_t)flat * L;
  float v[L];
  float nrm2 = 0.f;
  #pragma unroll
  for (int c = 0; c < L; c++) { v[c] = e[c]; emb[g * L + c] = v[c]; nrm2 += v[c] * v[c]; }
  float nrm = fmaxf(sqrtf(nrm2), 1e-12f);
  #pragma unroll
  for (int c = 0; c < L; c++) nemb[g * L + c] = v[c] / nrm;
  lab[g] = conf_t[flat];
  const float* tr = targets + ((size_t)b * O + j) * 9;
  qp[g * 3 + 0] = tr[5]; qp[g * 3 + 1] = tr[6]; qp[g * 3 + 2] = tr[7];
}

// ---------- K5b: pairwise dist / masks / desk ----------
__global__ void k_pairs(const float* __restrict__ emb, const float* __restrict__ nemb,
                        const float* __restrict__ qp, const int* __restrict__ lab,
                        Accum* acc, float* __restrict__ dist,
                        unsigned long long* __restrict__ posmask,
                        unsigned long long* __restrict__ negmask) {
  __shared__ float ei[L], ni[L], qi[3];
  __shared__ int li, Pc_s;
  __shared__ double sbuf[256];
  int i = blockIdx.x, j = threadIdx.x;
  if (j < L) { ei[j] = emb[i * L + j]; ni[j] = nemb[i * L + j]; }
  if (j < 3) qi[j] = qp[i * 3 + j];
  if (j == 0) { li = lab[i]; Pc_s = acc->Pc; }
  __syncthreads();
  int Pc = Pc_s;
  bool vi = (i < Pc), vj = (j < Pc);
  float sq = 0.f, esq = 0.f;
  #pragma unroll
  for (int c = 0; c < L; c++) {
    float dn = ni[c] - nemb[j * L + c]; sq += dn * dn;
    float de = ei[c] - emb[j * L + c];  esq += de * de;
  }
  float dd = sqrtf(fmaxf(sq, 1e-12f));
  dist[i * 256 + j] = dd;
  float qsq = 0.f;
  #pragma unroll
  for (int c = 0; c < 3; c++) { float dq = qi[c] - qp[j * 3 + c]; qsq += dq * dq; }
  bool vp = vi && vj && (i != j);
  bool same = (li == lab[j]);
  bool pp = vp && same && (dd > 0.2f);
  bool np = vp && !same && (dd < 0.8f);
  unsigned long long pb = __ballot(pp), nb = __ballot(np);
  int lane = j & 63, wave = j >> 6;
  if (lane == 0) {
    posmask[i * 4 + wave] = pb;
    negmask[i * 4 + wave] = nb;
    if (pb) atomicAdd(&acc->n_pp, (unsigned long long)__popcll(pb));
    if (nb) atomicAdd(&acc->n_np, (unsigned long long)__popcll(nb));
  }
  float diff = esq - qsq;                 // fp32 like the reference
  double dsk = pp ? (double)diff * (double)diff : 0.0;
  double tds = blockReduceSumD(dsk, sbuf);
  if (j == 0 && tds != 0.0) atomicAdd(&acc->desk, tds);
}

// ---------- K6: triple loop ----------
__global__ void k_trip(const float* __restrict__ dist,
                       const unsigned long long* __restrict__ posmask,
                       const unsigned long long* __restrict__ negmask, Accum* acc) {
  __shared__ float sd[256];
  __shared__ unsigned long long pm[4], nm[4];
  __shared__ double sbuf[256];
  int i = blockIdx.x, t = threadIdx.x;
  sd[t] = dist[i * 256 + t];
  if (t < 4) { pm[t] = posmask[i * 4 + t]; nm[t] = negmask[i * 4 + t]; }
  __syncthreads();
  bool anyp = (pm[0] | pm[1] | pm[2] | pm[3]) != 0ull;
  bool anyn = (nm[0] | nm[1] | nm[2] | nm[3]) != 0ull;
  double s = 0.0, c = 0.0;
  if (anyp && anyn) {
    for (int idx = t; idx < 65536; idx += 256) {
      int j = idx & 255, k = idx >> 8;
      if (((pm[j >> 6] >> (j & 63)) & 1ull) && ((nm[k >> 6] >> (k & 63)) & 1ull)) {
        float x = sd[j] - sd[k] + 0.2f;
        if (x > 0.f) { s += (double)x; c += 1.0; }
      }
    }
  }
  double ts = blockReduceSumD(s, sbuf);
  double tc = blockReduceSumD(c, sbuf);
  if (t == 0 && (ts != 0.0 || tc != 0.0)) {
    atomicAdd(&acc->trip_sum, ts);
    atomicAdd(&acc->trip_cnt, tc);
  }
}

// ---------- K7: finalize ----------
__global__ void k_final(const Accum* acc, float* out) {
  double N = (acc->total_pos > 0) ? (double)acc->total_pos : 1.0;
  out[0] = (float)(acc->loss_l / N);
  out[1] = (float)((acc->ce_pos + acc->ce_neg) / N);
  out[2] = (float)(acc->loss_p / N);
  double cnt = (acc->trip_cnt > 0.0) ? acc->trip_cnt : 1.0;
  double loss_t = acc->trip_sum / cnt;
  double npp = (acc->n_pp > 0ull) ? (double)acc->n_pp : 1.0;
  unsigned long long tot = acc->n_pp + acc->n_np;
  double denom = (tot > 0ull) ? (double)tot : 1.0;
  double Ldesk = acc->desk / npp + loss_t / denom;
  Ldesk = Ldesk / npp / 32.0;
  out[3] = (float)Ldesk;
  out[4] = (float)loss_t;
}

extern "C" void kernel_launch(void* const* d_in, const int* in_sizes, int n_in,
                              void* d_out, int out_size, void* d_ws, size_t ws_size,
                              hipStream_t stream) {
  const float* loc     = (const float*)d_in[0];
  const float* conf    = (const float*)d_in[1];
  const float* line    = (const float*)d_in[2];
  const float* pose    = (const float*)d_in[3];
  const float* dbox    = (const float*)d_in[4];
  const float* targets = (const float*)d_in[5];
  float* out = (float*)d_out;

  char* ws = (char*)d_ws;
  size_t off = 0;
  auto alloc = [&](size_t bytes) -> char* {
    char* p = ws + off;
    off += (bytes + 255) & ~(size_t)255;
    return p;
  };
  float* bt_ov    = (float*)alloc((size_t)BD * 4);
  int*   bt_idx   = (int*)  alloc((size_t)BD * 4);
  int*   conf_t   = (int*)  alloc((size_t)BD * 4);
  float* ce_mined = (float*)alloc((size_t)BD * 4);
  int*   posCnt   = (int*)  alloc(NCH * 4);
  int*   negCnt   = (int*)  alloc(NCH * 4);
  int*   posBase  = (int*)  alloc(NCH * 4);
  int*   negBase  = (int*)  alloc(NCH * 4);
  int*   posIdx   = (int*)  alloc(256 * 4);
  int*   negIdx   = (int*)  alloc(256 * 4);
  float* emb      = (float*)alloc(256 * L * 4);
  float* nemb     = (float*)alloc(256 * L * 4);
  float* qp       = (float*)alloc(256 * 3 * 4);
  int*   lab      = (int*)  alloc(256 * 4);
  float* dist     = (float*)alloc(256 * 256 * 4);
  unsigned long long* posmask = (unsigned long long*)alloc(256 * 4 * 8);
  unsigned long long* negmask = (unsigned long long*)alloc(256 * 4 * 8);
  Accum* acc      = (Accum*)alloc(sizeof(Accum));

  hipMemsetAsync(acc, 0, sizeof(Accum), stream);
  k_match   <<<B, 256, 0, stream>>>(dbox, targets, bt_ov, bt_idx);
  k_losses  <<<dim3((D + 255) / 256, B), 256, 0, stream>>>(loc, conf, pose, dbox, targets,
                                                           bt_ov, bt_idx, conf_t, ce_mined, acc);
  k_topk    <<<B, 256, 0, stream>>>(ce_mined, acc);
  k_selcount<<<NCH, 1024, 0, stream>>>(conf_t, posCnt, negCnt);
  k_selscan <<<1, 256, 0, stream>>>(posCnt, negCnt, posBase, negBase, acc);
  k_selwrite<<<NCH, 1024, 0, stream>>>(conf_t, posBase, negBase, posIdx, negIdx);
  k_gather  <<<1, 256, 0, stream>>>(line, targets, conf_t, bt_idx, posIdx, negIdx, acc,
                                    emb, nemb, qp, lab);
  k_pairs   <<<256, 256, 0, stream>>>(emb, nemb, qp, lab, acc, dist, posmask, negmask);
  k_trip    <<<256, 256, 0, stream>>>(dist, posmask, negmask, acc);
  k_final   <<<1, 1, 0, stream>>>(acc, out);
}

// Round 2
// 246.024 us; speedup vs baseline: 1.1821x; 1.1821x over previous
//
#include <hip/hip_runtime.h>
#include <hip/hip_bf16.h>
#include <cstdint>

#define B 32
#define D 8732
#define C 21
#define L 32
#define O 8
#define BD (B*D)
#define NCH ((BD + 1023) / 1024)   // 273 chunks of 1024

struct Accum {
  double loss_l, loss_p, ce_pos, ce_neg, desk, trip_sum, trip_cnt;
  unsigned long long n_pp, n_np;
  int num_pos[B];
  int total_pos;
  int Pc;
};

__device__ inline double blockReduceSumD(double v, double* sbuf) {
  int tid = threadIdx.x;
  sbuf[tid] = v; __syncthreads();
  for (int s = blockDim.x / 2; s > 0; s >>= 1) {
    if (tid < s) sbuf[tid] += sbuf[tid + s];
    __syncthreads();
  }
  double r = sbuf[0]; __syncthreads();
  return r;
}

__device__ inline double waveSumD(double v) {
  #pragma unroll
  for (int s = 32; s > 0; s >>= 1) v += __shfl_down(v, s, 64);
  return v;
}

// ---------- K1: matching (one block per batch) ----------
__global__ void k_match(const float* __restrict__ dbox, const float* __restrict__ targets,
                        float* __restrict__ bt_ov, int* __restrict__ bt_idx) {
  int b = blockIdx.x;
  int tid = threadIdx.x;
  __shared__ float tb[O][4];
  __shared__ float ta[O];
  __shared__ float sv[256];
  __shared__ int   si[256];
  __shared__ int   bp[O];
  if (tid < O) {
    const float* tr = targets + ((size_t)b * O + tid) * 9;
    tb[tid][0] = tr[0]; tb[tid][1] = tr[1]; tb[tid][2] = tr[2]; tb[tid][3] = tr[3];
    ta[tid] = (tr[2] - tr[0]) * (tr[3] - tr[1]);
  }
  __syncthreads();
  float pv[O]; int pi[O];
  #pragma unroll
  for (int t = 0; t < O; t++) { pv[t] = -1.0f; pi[t] = 0; }
  for (int d = tid; d < D; d += blockDim.x) {
    float4 db = *(const float4*)(dbox + d*4);
    float px1 = db.x - 0.5f*db.z, py1 = db.y - 0.5f*db.w;
    float px2 = db.x + 0.5f*db.z, py2 = db.y + 0.5f*db.w;
    float areaB = db.z * db.w;
    float bv = -1.0f; int bi = 0;
    #pragma unroll
    for (int t = 0; t < O; t++) {
      float lx = fmaxf(tb[t][0], px1), ly = fmaxf(tb[t][1], py1);
      float rx = fminf(tb[t][2], px2), ry = fminf(tb[t][3], py2);
      float iw = fmaxf(rx - lx, 0.f), ih = fmaxf(ry - ly, 0.f);
      float inter = iw * ih;
      float iou = inter / (ta[t] + areaB - inter);
      if (iou > bv) { bv = iou; bi = t; }                 // argmax axis=0: first max wins
      if (iou > pv[t]) { pv[t] = iou; pi[t] = d; }        // argmax axis=1 per truth
    }
    bt_ov[(size_t)b*D + d] = bv;
    bt_idx[(size_t)b*D + d] = bi;
  }
  // reduce best prior per truth (tie-break: smaller index)
  for (int t = 0; t < O; t++) {
    sv[tid] = pv[t]; si[tid] = pi[t];
    __syncthreads();
    for (int s = blockDim.x / 2; s > 0; s >>= 1) {
      if (tid < s) {
        if (sv[tid+s] > sv[tid] || (sv[tid+s] == sv[tid] && si[tid+s] < si[tid])) {
          sv[tid] = sv[tid+s]; si[tid] = si[tid+s];
        }
      }
      __syncthreads();
    }
    if (tid == 0) bp[t] = si[0];
    __syncthreads();
  }
  if (tid == 0) {
    // sequential overrides: numpy scatter semantics (last truth wins on dup)
    for (int t = 0; t < O; t++) {
      int dd = bp[t];
      bt_ov[(size_t)b*D + dd] = 2.0f;
      bt_idx[(size_t)b*D + dd] = t;
    }
  }
}

// ---------- K2: conf_t, ce, loc/pose losses (conf staged via LDS, coalesced) ----------
__global__ void k_losses(const float* __restrict__ loc, const float* __restrict__ conf,
                         const float* __restrict__ pose, const float* __restrict__ dbox,
                         const float* __restrict__ targets, const float* __restrict__ bt_ov,
                         const int* __restrict__ bt_idx, int* __restrict__ conf_t,
                         float* __restrict__ ce_mined, Accum* acc) {
  __shared__ float sconf[256 * C];   // 21504 B, stride-21 reads: 2-way bank alias = free
  __shared__ double sbuf[256];
  int b = blockIdx.y;
  int d0 = blockIdx.x * 256;
  int tid = threadIdx.x;
  int nd = D - d0; if (nd > 256) nd = 256;
  const float* cbase = conf + ((size_t)b * D + d0) * C;
  for (int i = tid; i < nd * C; i += 256) sconf[i] = cbase[i];
  __syncthreads();
  int d = d0 + tid;
  double ll = 0, lp = 0, cp = 0; int np = 0;
  if (d < D) {
    size_t bd = (size_t)b * D + d;
    int j = bt_idx[bd];
    float ov = bt_ov[bd];
    const float* tr = targets + ((size_t)b * O + j) * 9;
    int cls = (ov < 0.5f) ? 0 : ((int)tr[4] + 1);
    conf_t[bd] = cls;
    const float* x = sconf + tid * C;
    float m = x[0];
    #pragma unroll
    for (int c = 1; c < C; c++) m = fmaxf(m, x[c]);
    float s = 0.f;
    #pragma unroll
    for (int c = 0; c < C; c++) s += expf(x[c] - m);
    float ce = m + logf(s) - x[cls];
    if (cls > 0) {
      np = 1; cp = ce;
      ce_mined[bd] = 0.f;
      float4 db = *(const float4*)(dbox + d*4);
      float g0 = ((tr[0] + tr[2]) * 0.5f - db.x) / (0.1f * db.z);
      float g1 = ((tr[1] + tr[3]) * 0.5f - db.y) / (0.1f * db.w);
      float g2 = logf((tr[2] - tr[0]) / db.z) / 0.2f;
      float g3 = logf((tr[3] - tr[1]) / db.w) / 0.2f;
      float4 lo = *(const float4*)(loc + bd * 4);
      float dv, a;
      dv = lo.x - g0; a = fabsf(dv); ll += (double)((a < 1.f) ? 0.5f*dv*dv : a - 0.5f);
      dv = lo.y - g1; a = fabsf(dv); ll += (double)((a < 1.f) ? 0.5f*dv*dv : a - 0.5f);
      dv = lo.z - g2; a = fabsf(dv); ll += (double)((a < 1.f) ? 0.5f*dv*dv : a - 0.5f);
      dv = lo.w - g3; a = fabsf(dv); ll += (double)((a < 1.f) ? 0.5f*dv*dv : a - 0.5f);
      const float* po = pose + bd * 3;
      #pragma unroll
      for (int q = 0; q < 3; q++) {
        float pd = po[q] - tr[5 + q];
        lp += (double)pd * (double)pd;
      }
    } else {
      ce_mined[bd] = fmaxf(ce, 0.f);
    }
  }
  double tll = blockReduceSumD(ll, sbuf);
  double tlp = blockReduceSumD(lp, sbuf);
  double tcp = blockReduceSumD(cp, sbuf);
  double tnp = blockReduceSumD((double)np, sbuf);
  if (threadIdx.x == 0) {
    if (tll != 0.0) atomicAdd(&acc->loss_l, tll);
    if (tlp != 0.0) atomicAdd(&acc->loss_p, tlp);
    if (tcp != 0.0) atomicAdd(&acc->ce_pos, tcp);
    int inp = (int)(tnp + 0.5);
    if (inp) { atomicAdd(&acc->num_pos[b], inp); atomicAdd(&acc->total_pos, inp); }
  }
}

// ---------- K3: per-batch top-k negative CE sum (LDS-staged radix select) ----------
__global__ __launch_bounds__(1024) void k_topk(const float* __restrict__ ce_mined, Accum* acc) {
  int b = blockIdx.x;
  int tid = threadIdx.x;
  int lane = tid & 63, wav = tid >> 6;
  __shared__ float sce[D];            // 34928 B: all ce for this batch
  __shared__ int whist[16][256];      // per-wave hists: no cross-wave atomic serialization
  __shared__ int hist[256];
  __shared__ unsigned int sh_prefix;
  __shared__ int sh_k;
  __shared__ double wsum[16], wcnt[16];
  const float* ce = ce_mined + (size_t)b * D;
  for (int d = tid; d < D; d += 1024) sce[d] = ce[d];
  int k = acc->num_pos[b] * 3;
  if (k > D) k = D;
  __syncthreads();
  unsigned int prefix = 0; int kk = k;   // invariant: kk >= 1 (num_pos >= 1 always)
  for (int pass = 0; pass < 4; pass++) {
    int shift = 24 - 8 * pass;
    for (int i = tid; i < 16 * 256; i += 1024) ((int*)whist)[i] = 0;
    __syncthreads();
    unsigned int himask = (pass == 0) ? 0u : (0xFFFFFFFFu << (shift + 8));
    for (int d = tid; d < D; d += 1024) {
      unsigned int key = __float_as_uint(sce[d]);
      if ((key & himask) == (prefix & himask))
        atomicAdd(&whist[wav][(key >> shift) & 255], 1);
    }
    __syncthreads();
    if (tid < 256) {
      int h = 0;
      #pragma unroll
      for (int w = 0; w < 16; w++) h += whist[w][tid];
      hist[tid] = h;
    }
    __syncthreads();
    // digit select by wave 0: suffix-scan via shuffles, no serial loop
    if (tid < 64) {
      int l = tid;
      int h0 = hist[l*4], h1 = hist[l*4+1], h2 = hist[l*4+2], h3 = hist[l*4+3];
      int loc4 = h0 + h1 + h2 + h3;
      int suf = loc4;  // suffix sum over lane groups: suf[l] = sum_{l'>=l} loc4[l']
      #pragma unroll
      for (int s = 1; s < 64; s <<= 1) {
        int o = __shfl_down(suf, s, 64);
        if (l + s < 64) suf += o;
      }
      int snext = suf - loc4;          // suffix of bins >= (l+1)*4
      int s3 = snext + h3, s2 = s3 + h2, s1 = s2 + h1, s0 = s1 + h0;
      // exactly one (lane,slot) satisfies: max bin with suffix >= kk
      if (s3 >= kk && snext < kk) { sh_prefix = prefix | ((unsigned)(l*4+3) << shift); sh_k = kk - snext; }
      if (s2 >= kk && s3 < kk)    { sh_prefix = prefix | ((unsigned)(l*4+2) << shift); sh_k = kk - s3; }
      if (s1 >= kk && s2 < kk)    { sh_prefix = prefix | ((unsigned)(l*4+1) << shift); sh_k = kk - s2; }
      if (s0 >= kk && s1 < kk)    { sh_prefix = prefix | ((unsigned)(l*4+0) << shift); sh_k = kk - s1; }
    }
    __syncthreads();
    prefix = sh_prefix; kk = sh_k;
    __syncthreads();
  }
  float T = __uint_as_float(prefix);
  double sgt = 0.0; int cgt = 0;
  for (int d = tid; d < D; d += 1024) {
    float v = sce[d];
    if (__float_as_uint(v) > prefix) { sgt += (double)v; cgt++; }
  }
  double wv = waveSumD(sgt);
  double wc = waveSumD((double)cgt);
  if (lane == 0) { wsum[wav] = wv; wcnt[wav] = wc; }
  __syncthreads();
  if (tid == 0) {
    double tsg = 0, tcg = 0;
    #pragma unroll
    for (int w = 0; w < 16; w++) { tsg += wsum[w]; tcg += wcnt[w]; }
    atomicAdd(&acc->ce_neg, tsg + ((double)k - tcg) * (double)T);
  }
}

// ---------- K4: stable selection of first 256 pos / neg flat indices ----------
__global__ void k_selcount(const int* __restrict__ conf_t, int* __restrict__ posCnt,
                           int* __restrict__ negCnt) {
  int i = blockIdx.x * 1024 + threadIdx.x;
  int p = (i < BD) && (conf_t[i] > 0);
  int n = (i < BD) && (conf_t[i] == 0);
  __shared__ int sp, sn;
  if (threadIdx.x == 0) { sp = 0; sn = 0; }
  __syncthreads();
  unsigned long long pm = __ballot(p), nm = __ballot(n);
  if ((threadIdx.x & 63) == 0) { atomicAdd(&sp, __popcll(pm)); atomicAdd(&sn, __popcll(nm)); }
  __syncthreads();
  if (threadIdx.x == 0) { posCnt[blockIdx.x] = sp; negCnt[blockIdx.x] = sn; }
}

__global__ void k_selscan(const int* __restrict__ posCnt, const int* __restrict__ negCnt,
                          int* __restrict__ posBase, int* __restrict__ negBase, Accum* acc) {
  __shared__ int sp[NCH], sn[NCH];
  for (int c = threadIdx.x; c < NCH; c += blockDim.x) { sp[c] = posCnt[c]; sn[c] = negCnt[c]; }
  __syncthreads();
  if (threadIdx.x == 0) {
    int p = 0, n = 0;
    for (int c = 0; c < NCH; c++) {
      int tp = sp[c], tn = sn[c];
      sp[c] = p; sn[c] = n;
      p += tp; n += tn;
    }
    acc->Pc = (p < 256) ? p : 256;
  }
  __syncthreads();
  for (int c = threadIdx.x; c < NCH; c += blockDim.x) { posBase[c] = sp[c]; negBase[c] = sn[c]; }
}

__global__ void k_selwrite(const int* __restrict__ conf_t, const int* __restrict__ posBase,
                           const int* __restrict__ negBase, int* __restrict__ posIdx,
                           int* __restrict__ negIdx) {
  int ch = blockIdx.x;
  int pbase = posBase[ch], nbase = negBase[ch];
  if (pbase >= 256 && nbase >= 256) return;
  int i = ch * 1024 + threadIdx.x;
  int p = (i < BD) && (conf_t[i] > 0);
  int n = (i < BD) && (conf_t[i] == 0);
  unsigned long long pm = __ballot(p), nm = __ballot(n);
  int lane = threadIdx.x & 63, wave = threadIdx.x >> 6;
  __shared__ int wp[16], wn[16];
  if (lane == 0) { wp[wave] = __popcll(pm); wn[wave] = __popcll(nm); }
  __syncthreads();
  int pb = pbase, nb = nbase;
  for (int w = 0; w < wave; w++) { pb += wp[w]; nb += wn[w]; }
  unsigned long long lt = (lane == 0) ? 0ull : (~0ull >> (64 - lane));
  int prank = pb + __popcll(pm & lt);
  int nrank = nb + __popcll(nm & lt);
  if (p && prank < 256) posIdx[prank] = i;
  if (n && nrank < 256) negIdx[nrank] = i;
}

// ---------- K5a: gather embeddings / labels / poses ----------
__global__ void k_gather(const float* __restrict__ line, const float* __restrict__ targets,
                         const int* __restrict__ conf_t, const int* __restrict__ bt_idx,
                         const int* __restrict__ posIdx, const int* __restrict__ negIdx,
                         const Accum* acc, float* __restrict__ emb, float* __restrict__ nemb,
                         float* __restrict__ qp, int* __restrict__ lab) {
  int g = threadIdx.x;
  int Pc = acc->Pc;
  int flat = (g < Pc) ? posIdx[g] : negIdx[g - Pc];
  int b = flat / D, j = bt_idx[flat];
  const float4* e4 = (const float4*)(line + (size_t)flat * L);
  float4* o4 = (float4*)(emb + g * L);
  float4* n4 = (float4*)(nemb + g * L);
  float4 v[8];
  float nrm2 = 0.f;
  #pragma unroll
  for (int c = 0; c < 8; c++) {
    v[c] = e4[c];
    o4[c] = v[c];
    nrm2 += v[c].x*v[c].x + v[c].y*v[c].y + v[c].z*v[c].z + v[c].w*v[c].w;
  }
  float inv = 1.f / fmaxf(sqrtf(nrm2), 1e-12f);
  #pragma unroll
  for (int c = 0; c < 8; c++) {
    float4 t = v[c];
    t.x *= inv; t.y *= inv; t.z *= inv; t.w *= inv;
    n4[c] = t;
  }
  lab[g] = conf_t[flat];
  const float* tr = targets + ((size_t)b * O + j) * 9;
  qp[g * 3 + 0] = tr[5]; qp[g * 3 + 1] = tr[6]; qp[g * 3 + 2] = tr[7];
}

// ---------- K5b: pairwise dist / masks / desk ----------
__global__ void k_pairs(const float* __restrict__ emb, const float* __restrict__ nemb,
                        const float* __restrict__ qp, const int* __restrict__ lab,
                        Accum* acc, float* __restrict__ dist,
                        unsigned long long* __restrict__ posmask,
                        unsigned long long* __restrict__ negmask) {
  __shared__ float ei[L], ni[L], qi[3];
  __shared__ int li, Pc_s;
  __shared__ double sbuf[256];
  int i = blockIdx.x, j = threadIdx.x;
  if (j < L) { ei[j] = emb[i * L + j]; ni[j] = nemb[i * L + j]; }
  if (j < 3) qi[j] = qp[i * 3 + j];
  if (j == 0) { li = lab[i]; Pc_s = acc->Pc; }
  __syncthreads();
  int Pc = Pc_s;
  bool vi = (i < Pc), vj = (j < Pc);
  const float4* nj4 = (const float4*)(nemb + j * L);
  const float4* ej4 = (const float4*)(emb + j * L);
  float sq = 0.f, esq = 0.f;
  #pragma unroll
  for (int c = 0; c < 8; c++) {
    float4 nn = nj4[c], ee = ej4[c];
    float d0 = ni[c*4+0] - nn.x, d1 = ni[c*4+1] - nn.y, d2 = ni[c*4+2] - nn.z, d3 = ni[c*4+3] - nn.w;
    sq += d0*d0 + d1*d1 + d2*d2 + d3*d3;
    float e0 = ei[c*4+0] - ee.x, e1 = ei[c*4+1] - ee.y, e2 = ei[c*4+2] - ee.z, e3 = ei[c*4+3] - ee.w;
    esq += e0*e0 + e1*e1 + e2*e2 + e3*e3;
  }
  float dd = sqrtf(fmaxf(sq, 1e-12f));
  dist[i * 256 + j] = dd;
  float qsq = 0.f;
  #pragma unroll
  for (int c = 0; c < 3; c++) { float dq = qi[c] - qp[j * 3 + c]; qsq += dq * dq; }
  bool vp = vi && vj && (i != j);
  bool same = (li == lab[j]);
  bool pp = vp && same && (dd > 0.2f);
  bool np = vp && !same && (dd < 0.8f);
  unsigned long long pb = __ballot(pp), nb = __ballot(np);
  int lane = j & 63, wave = j >> 6;
  if (lane == 0) {
    posmask[i * 4 + wave] = pb;
    negmask[i * 4 + wave] = nb;
    if (pb) atomicAdd(&acc->n_pp, (unsigned long long)__popcll(pb));
    if (nb) atomicAdd(&acc->n_np, (unsigned long long)__popcll(nb));
  }
  float diff = esq - qsq;                 // fp32 like the reference
  double dsk = pp ? (double)diff * (double)diff : 0.0;
  double tds = blockReduceSumD(dsk, sbuf);
  if (j == 0 && tds != 0.0) atomicAdd(&acc->desk, tds);
}

// ---------- K6: triple loop ----------
__global__ void k_trip(const float* __restrict__ dist,
                       const unsigned long long* __restrict__ posmask,
                       const unsigned long long* __restrict__ negmask, Accum* acc) {
  __shared__ float sd[256];
  __shared__ unsigned long long pm[4], nm[4];
  __shared__ double sbuf[256];
  int i = blockIdx.x, t = threadIdx.x;
  sd[t] = dist[i * 256 + t];
  if (t < 4) { pm[t] = posmask[i * 4 + t]; nm[t] = negmask[i * 4 + t]; }
  __syncthreads();
  bool anyp = (pm[0] | pm[1] | pm[2] | pm[3]) != 0ull;
  bool anyn = (nm[0] | nm[1] | nm[2] | nm[3]) != 0ull;
  double s = 0.0, c = 0.0;
  if (anyp && anyn) {
    for (int idx = t; idx < 65536; idx += 256) {
      int j = idx & 255, k = idx >> 8;
      if (((pm[j >> 6] >> (j & 63)) & 1ull) && ((nm[k >> 6] >> (k & 63)) & 1ull)) {
        float x = sd[j] - sd[k] + 0.2f;
        if (x > 0.f) { s += (double)x; c += 1.0; }
      }
    }
  }
  double ts = blockReduceSumD(s, sbuf);
  double tc = blockReduceSumD(c, sbuf);
  if (t == 0 && (ts != 0.0 || tc != 0.0)) {
    atomicAdd(&acc->trip_sum, ts);
    atomicAdd(&acc->trip_cnt, tc);
  }
}

// ---------- K7: finalize ----------
__global__ void k_final(const Accum* acc, float* out) {
  double N = (acc->total_pos > 0) ? (double)acc->total_pos : 1.0;
  out[0] = (float)(acc->loss_l / N);
  out[1] = (float)((acc->ce_pos + acc->ce_neg) / N);
  out[2] = (float)(acc->loss_p / N);
  double cnt = (acc->trip_cnt > 0.0) ? acc->trip_cnt : 1.0;
  double loss_t = acc->trip_sum / cnt;
  double npp = (acc->n_pp > 0ull) ? (double)acc->n_pp : 1.0;
  unsigned long long tot = acc->n_pp + acc->n_np;
  double denom = (tot > 0ull) ? (double)tot : 1.0;
  double Ldesk = acc->desk / npp + loss_t / denom;
  Ldesk = Ldesk / npp / 32.0;
  out[3] = (float)Ldesk;
  out[4] = (float)loss_t;
}

extern "C" void kernel_launch(void* const* d_in, const int* in_sizes, int n_in,
                              void* d_out, int out_size, void* d_ws, size_t ws_size,
                              hipStream_t stream) {
  const float* loc     = (const float*)d_in[0];
  const float* conf    = (const float*)d_in[1];
  const float* line    = (const float*)d_in[2];
  const float* pose    = (const float*)d_in[3];
  const float* dbox    = (const float*)d_in[4];
  const float* targets = (const float*)d_in[5];
  float* out = (float*)d_out;

  char* ws = (char*)d_ws;
  size_t off = 0;
  auto alloc = [&](size_t bytes) -> char* {
    char* p = ws + off;
    off += (bytes + 255) & ~(size_t)255;
    return p;
  };
  float* bt_ov    = (float*)alloc((size_t)BD * 4);
  int*   bt_idx   = (int*)  alloc((size_t)BD * 4);
  int*   conf_t   = (int*)  alloc((size_t)BD * 4);
  float* ce_mined = (float*)alloc((size_t)BD * 4);
  int*   posCnt   = (int*)  alloc(NCH * 4);
  int*   negCnt   = (int*)  alloc(NCH * 4);
  int*   posBase  = (int*)  alloc(NCH * 4);
  int*   negBase  = (int*)  alloc(NCH * 4);
  int*   posIdx   = (int*)  alloc(256 * 4);
  int*   negIdx   = (int*)  alloc(256 * 4);
  float* emb      = (float*)alloc(256 * L * 4);
  float* nemb     = (float*)alloc(256 * L * 4);
  float* qp       = (float*)alloc(256 * 3 * 4);
  int*   lab      = (int*)  alloc(256 * 4);
  float* dist     = (float*)alloc(256 * 256 * 4);
  unsigned long long* posmask = (unsigned long long*)alloc(256 * 4 * 8);
  unsigned long long* negmask = (unsigned long long*)alloc(256 * 4 * 8);
  Accum* acc      = (Accum*)alloc(sizeof(Accum));

  hipMemsetAsync(acc, 0, sizeof(Accum), stream);
  k_match   <<<B, 256, 0, stream>>>(dbox, targets, bt_ov, bt_idx);
  k_losses  <<<dim3((D + 255) / 256, B), 256, 0, stream>>>(loc, conf, pose, dbox, targets,
                                                           bt_ov, bt_idx, conf_t, ce_mined, acc);
  k_topk    <<<B, 1024, 0, stream>>>(ce_mined, acc);
  k_selcount<<<NCH, 1024, 0, stream>>>(conf_t, posCnt, negCnt);
  k_selscan <<<1, 256, 0, stream>>>(posCnt, negCnt, posBase, negBase, acc);
  k_selwrite<<<NCH, 1024, 0, stream>>>(conf_t, posBase, negBase, posIdx, negIdx);
  k_gather  <<<1, 256, 0, stream>>>(line, targets, conf_t, bt_idx, posIdx, negIdx, acc,
                                    emb, nemb, qp, lab);
  k_pairs   <<<256, 256, 0, stream>>>(emb, nemb, qp, lab, acc, dist, posmask, negmask);
  k_trip    <<<256, 256, 0, stream>>>(dist, posmask, negmask, acc);
  k_final   <<<1, 1, 0, stream>>>(acc, out);
}

// Round 3
// 208.202 us; speedup vs baseline: 1.3969x; 1.1817x over previous
//
#include <hip/hip_runtime.h>
#include <hip/hip_bf16.h>
#include <cstdint>

#define B 32
#define D 8732
#define C 21
#define L 32
#define O 8
#define BD (B*D)
#define NBX 35                 // ceil(8732/256)
#define NCH2 (NBX*B)           // 1120 chunks of 256 (flat order: b-major, d-minor)

struct Accum {
  double loss_l, loss_p, ce_pos, ce_neg, desk, trip_sum, trip_cnt;
  unsigned long long n_pp, n_np;
  int num_pos[B];
  int total_pos;
  int Pc;
};

__device__ inline double waveSumD(double v) {
  #pragma unroll
  for (int s = 32; s > 0; s >>= 1) v += __shfl_down(v, s, 64);
  return v;
}

__device__ inline float iou_one(float tx1, float ty1, float tx2, float ty2, float ta,
                                float px1, float py1, float px2, float py2, float areaB) {
  float lx = fmaxf(tx1, px1), ly = fmaxf(ty1, py1);
  float rx = fminf(tx2, px2), ry = fminf(ty2, py2);
  float iw = fmaxf(rx - lx, 0.f), ih = fmaxf(ry - ly, 0.f);
  float inter = iw * ih;
  return inter / (ta + areaB - inter);
}

// ---------- K1: per-(b,t) best prior via packed atomicMax ----------
__global__ void k_bestprior(const float* __restrict__ dbox, const float* __restrict__ targets,
                            unsigned long long* __restrict__ bp) {
  int b = blockIdx.y;
  int d0 = blockIdx.x * 256;
  int tid = threadIdx.x;
  __shared__ float tb[O][4];
  __shared__ float ta[O];
  __shared__ unsigned long long wm[4][O];
  if (tid < O) {
    const float* tr = targets + ((size_t)b * O + tid) * 9;
    tb[tid][0] = tr[0]; tb[tid][1] = tr[1]; tb[tid][2] = tr[2]; tb[tid][3] = tr[3];
    ta[tid] = (tr[2] - tr[0]) * (tr[3] - tr[1]);
  }
  __syncthreads();
  int d = d0 + tid;
  unsigned long long key[O];
  if (d < D) {
    float4 db = *(const float4*)(dbox + (size_t)d * 4);
    float px1 = db.x - 0.5f*db.z, py1 = db.y - 0.5f*db.w;
    float px2 = db.x + 0.5f*db.z, py2 = db.y + 0.5f*db.w;
    float areaB = db.z * db.w;
    #pragma unroll
    for (int t = 0; t < O; t++) {
      float iou = iou_one(tb[t][0], tb[t][1], tb[t][2], tb[t][3], ta[t],
                          px1, py1, px2, py2, areaB);
      key[t] = ((unsigned long long)__float_as_uint(iou) << 32)
             | (unsigned long long)(0xFFFFFFFFu - (unsigned)d);   // tie -> smaller d
    }
  } else {
    #pragma unroll
    for (int t = 0; t < O; t++) key[t] = 0ull;
  }
  int lane = tid & 63, wav = tid >> 6;
  #pragma unroll
  for (int t = 0; t < O; t++) {
    unsigned long long k = key[t];
    #pragma unroll
    for (int s = 32; s > 0; s >>= 1) {
      unsigned long long o = __shfl_down(k, s, 64);
      if (o > k) k = o;
    }
    if (lane == 0) wm[wav][t] = k;
  }
  __syncthreads();
  if (tid < O) {
    unsigned long long k = wm[0][tid];
    #pragma unroll
    for (int w = 1; w < 4; w++) if (wm[w][tid] > k) k = wm[w][tid];
    atomicMax(&bp[b * O + tid], k);
  }
}

// ---------- K2: conf_t, ce, loc/pose losses, fused pos counts ----------
__global__ void k_losses(const float* __restrict__ loc, const float* __restrict__ conf,
                         const float* __restrict__ pose, const float* __restrict__ dbox,
                         const float* __restrict__ targets,
                         const unsigned long long* __restrict__ bp,
                         int* __restrict__ conf_t, float* __restrict__ ce_mined,
                         int* __restrict__ posCnt, Accum* acc) {
  __shared__ __align__(16) float sconf[256 * C];
  __shared__ float tb[O][4], ta[O], tl[O], tp_[O][3];
  __shared__ int bpd[O];
  __shared__ double wred[4][3];
  __shared__ int swp[4];
  int b = blockIdx.y;
  int d0 = blockIdx.x * 256;
  int tid = threadIdx.x;
  int nd = D - d0; if (nd > 256) nd = 256;
  if (tid < O) {
    const float* tr = targets + ((size_t)b * O + tid) * 9;
    tb[tid][0] = tr[0]; tb[tid][1] = tr[1]; tb[tid][2] = tr[2]; tb[tid][3] = tr[3];
    ta[tid] = (tr[2] - tr[0]) * (tr[3] - tr[1]);
    tl[tid] = tr[4];
    tp_[tid][0] = tr[5]; tp_[tid][1] = tr[6]; tp_[tid][2] = tr[7];
  }
  if (tid >= 64 && tid < 64 + O) {
    unsigned long long k = bp[b * O + (tid - 64)];
    bpd[tid - 64] = (int)(0xFFFFFFFFu - (unsigned)(k & 0xFFFFFFFFull));
  }
  const float* cbase = conf + ((size_t)b * D + d0) * C;
  int nf4 = nd * C / 4;                      // 256*21 and 28*21 both divisible by 4
  for (int i = tid; i < nf4; i += 256)
    ((float4*)sconf)[i] = ((const float4*)cbase)[i];
  __syncthreads();
  int d = d0 + tid;
  double ll = 0, lp = 0, cp = 0;
  int cls = -1;
  if (d < D) {
    size_t bd = (size_t)b * D + d;
    float4 db = *(const float4*)(dbox + (size_t)d * 4);
    float px1 = db.x - 0.5f*db.z, py1 = db.y - 0.5f*db.w;
    float px2 = db.x + 0.5f*db.z, py2 = db.y + 0.5f*db.w;
    float areaB = db.z * db.w;
    float bv = -1.0f; int bi = 0;
    #pragma unroll
    for (int t = 0; t < O; t++) {
      float iou = iou_one(tb[t][0], tb[t][1], tb[t][2], tb[t][3], ta[t],
                          px1, py1, px2, py2, areaB);
      if (iou > bv) { bv = iou; bi = t; }    // argmax over truths: first max wins
    }
    #pragma unroll
    for (int t = O - 1; t >= 0; t--)         // numpy scatter: last truth wins
      if (bpd[t] == d) { bi = t; bv = 2.0f; break; }
    cls = (bv < 0.5f) ? 0 : ((int)tl[bi] + 1);
    conf_t[bd] = cls;
    const float* x = sconf + tid * C;
    float m = x[0];
    #pragma unroll
    for (int c = 1; c < C; c++) m = fmaxf(m, x[c]);
    float s = 0.f;
    #pragma unroll
    for (int c = 0; c < C; c++) s += expf(x[c] - m);
    float ce = m + logf(s) - x[cls];
    if (cls > 0) {
      cp = ce;
      ce_mined[bd] = 0.f;
      float g0 = ((tb[bi][0] + tb[bi][2]) * 0.5f - db.x) / (0.1f * db.z);
      float g1 = ((tb[bi][1] + tb[bi][3]) * 0.5f - db.y) / (0.1f * db.w);
      float g2 = logf((tb[bi][2] - tb[bi][0]) / db.z) / 0.2f;
      float g3 = logf((tb[bi][3] - tb[bi][1]) / db.w) / 0.2f;
      float4 lo = *(const float4*)(loc + bd * 4);
      float dv, a;
      dv = lo.x - g0; a = fabsf(dv); ll += (double)((a < 1.f) ? 0.5f*dv*dv : a - 0.5f);
      dv = lo.y - g1; a = fabsf(dv); ll += (double)((a < 1.f) ? 0.5f*dv*dv : a - 0.5f);
      dv = lo.z - g2; a = fabsf(dv); ll += (double)((a < 1.f) ? 0.5f*dv*dv : a - 0.5f);
      dv = lo.w - g3; a = fabsf(dv); ll += (double)((a < 1.f) ? 0.5f*dv*dv : a - 0.5f);
      const float* po = pose + bd * 3;
      #pragma unroll
      for (int q = 0; q < 3; q++) {
        float pd = po[q] - tp_[bi][q];
        lp += (double)pd * (double)pd;
      }
    } else {
      ce_mined[bd] = fmaxf(ce, 0.f);
    }
  }
  bool p = (cls > 0);
  unsigned long long pm = __ballot(p);
  int lane = tid & 63, wav = tid >> 6;
  double a0 = waveSumD(ll), a1 = waveSumD(lp), a2 = waveSumD(cp);
  if (lane == 0) {
    wred[wav][0] = a0; wred[wav][1] = a1; wred[wav][2] = a2;
    swp[wav] = __popcll(pm);
  }
  __syncthreads();
  if (tid == 0) {
    double tll = wred[0][0] + wred[1][0] + wred[2][0] + wred[3][0];
    double tlp = wred[0][1] + wred[1][1] + wred[2][1] + wred[3][1];
    double tcp = wred[0][2] + wred[1][2] + wred[2][2] + wred[3][2];
    int pc = swp[0] + swp[1] + swp[2] + swp[3];
    posCnt[b * NBX + blockIdx.x] = pc;
    if (tll != 0.0) atomicAdd(&acc->loss_l, tll);
    if (tlp != 0.0) atomicAdd(&acc->loss_p, tlp);
    if (tcp != 0.0) atomicAdd(&acc->ce_pos, tcp);
    if (pc) { atomicAdd(&acc->num_pos[b], pc); atomicAdd(&acc->total_pos, pc); }
  }
}

// ---------- K3: per-batch top-k negative CE sum (LDS-staged radix select) ----------
__global__ __launch_bounds__(1024) void k_topk(const float* __restrict__ ce_mined, Accum* acc) {
  int b = blockIdx.x;
  int tid = threadIdx.x;
  int lane = tid & 63, wav = tid >> 6;
  __shared__ __align__(16) float sce[D];
  __shared__ int whist[16][256];
  __shared__ int hist[256];
  __shared__ unsigned int sh_prefix;
  __shared__ int sh_k;
  __shared__ double wsum[16], wcnt[16];
  const float* ce = ce_mined + (size_t)b * D;
  for (int i = tid; i < D / 4; i += 1024)
    ((float4*)sce)[i] = ((const float4*)ce)[i];      // 8732 % 4 == 0
  int k = acc->num_pos[b] * 3;
  if (k > D) k = D;
  __syncthreads();
  unsigned int prefix = 0; int kk = k;   // kk >= 1 (num_pos >= 1 always)
  for (int pass = 0; pass < 4; pass++) {
    int shift = 24 - 8 * pass;
    for (int i = tid; i < 16 * 256; i += 1024) ((int*)whist)[i] = 0;
    __syncthreads();
    unsigned int himask = (pass == 0) ? 0u : (0xFFFFFFFFu << (shift + 8));
    for (int d = tid; d < D; d += 1024) {
      unsigned int key = __float_as_uint(sce[d]);
      if ((key & himask) == (prefix & himask))
        atomicAdd(&whist[wav][(key >> shift) & 255], 1);
    }
    __syncthreads();
    if (tid < 256) {
      int h = 0;
      #pragma unroll
      for (int w = 0; w < 16; w++) h += whist[w][tid];
      hist[tid] = h;
    }
    __syncthreads();
    if (tid < 64) {
      int l = tid;
      int h0 = hist[l*4], h1 = hist[l*4+1], h2 = hist[l*4+2], h3 = hist[l*4+3];
      int loc4 = h0 + h1 + h2 + h3;
      int suf = loc4;
      #pragma unroll
      for (int s = 1; s < 64; s <<= 1) {
        int o = __shfl_down(suf, s, 64);
        if (l + s < 64) suf += o;
      }
      int snext = suf - loc4;
      int s3 = snext + h3, s2 = s3 + h2, s1 = s2 + h1, s0 = s1 + h0;
      if (s3 >= kk && snext < kk) { sh_prefix = prefix | ((unsigned)(l*4+3) << shift); sh_k = kk - snext; }
      if (s2 >= kk && s3 < kk)    { sh_prefix = prefix | ((unsigned)(l*4+2) << shift); sh_k = kk - s3; }
      if (s1 >= kk && s2 < kk)    { sh_prefix = prefix | ((unsigned)(l*4+1) << shift); sh_k = kk - s2; }
      if (s0 >= kk && s1 < kk)    { sh_prefix = prefix | ((unsigned)(l*4+0) << shift); sh_k = kk - s1; }
    }
    __syncthreads();
    prefix = sh_prefix; kk = sh_k;
    __syncthreads();
  }
  float T = __uint_as_float(prefix);
  double sgt = 0.0; int cgt = 0;
  for (int d = tid; d < D; d += 1024) {
    float v = sce[d];
    if (__float_as_uint(v) > prefix) { sgt += (double)v; cgt++; }
  }
  double wv = waveSumD(sgt);
  double wc = waveSumD((double)cgt);
  if (lane == 0) { wsum[wav] = wv; wcnt[wav] = wc; }
  __syncthreads();
  if (tid == 0) {
    double tsg = 0, tcg = 0;
    #pragma unroll
    for (int w = 0; w < 16; w++) { tsg += wsum[w]; tcg += wcnt[w]; }
    atomicAdd(&acc->ce_neg, tsg + ((double)k - tcg) * (double)T);
  }
}

// ---------- K4: parallel exclusive scan of per-chunk positive counts ----------
__global__ __launch_bounds__(1024) void k_selscan(const int* __restrict__ posCnt,
                                                  int* __restrict__ posBase, Accum* acc) {
  __shared__ int sp[2048];
  int tid = threadIdx.x;
  for (int i = tid; i < 2048; i += 1024) sp[i] = (i < NCH2) ? posCnt[i] : 0;
  __syncthreads();
  for (int s = 1; s < 2048; s <<= 1) {
    int i0 = tid, i1 = tid + 1024;
    int v0 = sp[i0] + ((i0 >= s) ? sp[i0 - s] : 0);
    int v1 = sp[i1] + ((i1 >= s) ? sp[i1 - s] : 0);
    __syncthreads();
    sp[i0] = v0; sp[i1] = v1;
    __syncthreads();
  }
  for (int i = tid; i < NCH2; i += 1024) posBase[i] = sp[i] - posCnt[i];  // exclusive
  if (tid == 0) {
    int tp = acc->total_pos;
    acc->Pc = (tp < 256) ? tp : 256;
  }
}

// ---------- K5: write first-256 positive flat indices (stable) ----------
__global__ void k_selwrite(const int* __restrict__ conf_t, const int* __restrict__ posBase,
                           int* __restrict__ posIdx) {
  int ch = blockIdx.x;
  int pbase = posBase[ch];
  if (pbase >= 256) return;
  int b = ch / NBX, cx = ch - b * NBX;
  int dd = cx * 256 + threadIdx.x;
  int i = b * D + dd;
  bool p = (dd < D) && (conf_t[i] > 0);
  unsigned long long pm = __ballot(p);
  int lane = threadIdx.x & 63, wave = threadIdx.x >> 6;
  __shared__ int wp[4];
  if (lane == 0) wp[wave] = __popcll(pm);
  __syncthreads();
  int pb = pbase;
  for (int w = 0; w < wave; w++) pb += wp[w];
  unsigned long long lt = (lane == 0) ? 0ull : (~0ull >> (64 - lane));
  int prank = pb + __popcll(pm & lt);
  if (p && prank < 256) posIdx[prank] = i;
}

// ---------- K6: gather embeddings / labels / poses for the Pc positives ----------
__global__ void k_gather(const float* __restrict__ line, const float* __restrict__ targets,
                         const int* __restrict__ conf_t, const unsigned long long* __restrict__ bp,
                         const float* __restrict__ dbox, const int* __restrict__ posIdx,
                         const Accum* acc, float* __restrict__ emb, float* __restrict__ nemb,
                         float* __restrict__ qp, int* __restrict__ lab) {
  __shared__ float st[B * O * 9];      // 9216 B: all targets
  __shared__ int sbp[B * O];
  int g = threadIdx.x;
  for (int i = g; i < B * O * 9; i += 256) st[i] = targets[i];
  {
    unsigned long long k = bp[g];      // 256 entries exactly
    sbp[g] = (int)(0xFFFFFFFFu - (unsigned)(k & 0xFFFFFFFFull));
  }
  __syncthreads();
  int Pc = acc->Pc;
  if (g >= Pc) return;                 // invalid rows never contribute (masked by Pc)
  int flat = posIdx[g];
  int b = flat / D, d = flat - b * D;
  float4 db = *(const float4*)(dbox + (size_t)d * 4);
  float px1 = db.x - 0.5f*db.z, py1 = db.y - 0.5f*db.w;
  float px2 = db.x + 0.5f*db.z, py2 = db.y + 0.5f*db.w;
  float areaB = db.z * db.w;
  float bv = -1.0f; int bi = 0;
  #pragma unroll
  for (int t = 0; t < O; t++) {
    const float* tr = st + (b * O + t) * 9;
    float ta = (tr[2] - tr[0]) * (tr[3] - tr[1]);
    float iou = iou_one(tr[0], tr[1], tr[2], tr[3], ta, px1, py1, px2, py2, areaB);
    if (iou > bv) { bv = iou; bi = t; }
  }
  #pragma unroll
  for (int t = O - 1; t >= 0; t--)
    if (sbp[b * O + t] == d) { bi = t; break; }
  const float4* e4 = (const float4*)(line + (size_t)flat * L);
  float4* o4 = (float4*)(emb + g * L);
  float4* n4 = (float4*)(nemb + g * L);
  float4 v[8];
  float nrm2 = 0.f;
  #pragma unroll
  for (int c = 0; c < 8; c++) {
    v[c] = e4[c];
    o4[c] = v[c];
    nrm2 += v[c].x*v[c].x + v[c].y*v[c].y + v[c].z*v[c].z + v[c].w*v[c].w;
  }
  float inv = 1.f / fmaxf(sqrtf(nrm2), 1e-12f);
  #pragma unroll
  for (int c = 0; c < 8; c++) {
    float4 t = v[c];
    t.x *= inv; t.y *= inv; t.z *= inv; t.w *= inv;
    n4[c] = t;
  }
  lab[g] = conf_t[flat];
  const float* tr = st + (b * O + bi) * 9;
  qp[g * 3 + 0] = tr[5]; qp[g * 3 + 1] = tr[6]; qp[g * 3 + 2] = tr[7];
}

// ---------- K7: pairwise dist / masks / desk ----------
__global__ void k_pairs(const float* __restrict__ emb, const float* __restrict__ nemb,
                        const float* __restrict__ qp, const int* __restrict__ lab,
                        Accum* acc, float* __restrict__ dist,
                        unsigned long long* __restrict__ posmask,
                        unsigned long long* __restrict__ negmask) {
  __shared__ float ei[L], ni[L], qi[3];
  __shared__ int li, Pc_s;
  __shared__ double wred[4];
  int i = blockIdx.x, j = threadIdx.x;
  if (j < L) { ei[j] = emb[i * L + j]; ni[j] = nemb[i * L + j]; }
  if (j < 3) qi[j] = qp[i * 3 + j];
  if (j == 0) { li = lab[i]; Pc_s = acc->Pc; }
  __syncthreads();
  int Pc = Pc_s;
  bool vi = (i < Pc), vj = (j < Pc);
  const float4* nj4 = (const float4*)(nemb + j * L);
  const float4* ej4 = (const float4*)(emb + j * L);
  float sq = 0.f, esq = 0.f;
  #pragma unroll
  for (int c = 0; c < 8; c++) {
    float4 nn = nj4[c], ee = ej4[c];
    float d0 = ni[c*4+0] - nn.x, d1 = ni[c*4+1] - nn.y, d2 = ni[c*4+2] - nn.z, d3 = ni[c*4+3] - nn.w;
    sq += d0*d0 + d1*d1 + d2*d2 + d3*d3;
    float e0 = ei[c*4+0] - ee.x, e1 = ei[c*4+1] - ee.y, e2 = ei[c*4+2] - ee.z, e3 = ei[c*4+3] - ee.w;
    esq += e0*e0 + e1*e1 + e2*e2 + e3*e3;
  }
  float dd = sqrtf(fmaxf(sq, 1e-12f));
  dist[i * 256 + j] = dd;
  float qsq = 0.f;
  #pragma unroll
  for (int c = 0; c < 3; c++) { float dq = qi[c] - qp[j * 3 + c]; qsq += dq * dq; }
  bool vp = vi && vj && (i != j);
  bool same = (li == lab[j]);
  bool pp = vp && same && (dd > 0.2f);
  bool np = vp && !same && (dd < 0.8f);
  unsigned long long pb = __ballot(pp), nb = __ballot(np);
  int lane = j & 63, wave = j >> 6;
  if (lane == 0) {
    posmask[i * 4 + wave] = pb;
    negmask[i * 4 + wave] = nb;
    if (pb) atomicAdd(&acc->n_pp, (unsigned long long)__popcll(pb));
    if (nb) atomicAdd(&acc->n_np, (unsigned long long)__popcll(nb));
  }
  float diff = esq - qsq;
  double dsk = pp ? (double)diff * (double)diff : 0.0;
  double w = waveSumD(dsk);
  if (lane == 0) wred[wave] = w;
  __syncthreads();
  if (j == 0) {
    double t = wred[0] + wred[1] + wred[2] + wred[3];
    if (t != 0.0) atomicAdd(&acc->desk, t);
  }
}

// ---------- K8: triple loop ----------
__global__ void k_trip(const float* __restrict__ dist,
                       const unsigned long long* __restrict__ posmask,
                       const unsigned long long* __restrict__ negmask, Accum* acc) {
  __shared__ float sd[256];
  __shared__ unsigned long long pm[4], nm[4];
  __shared__ double wredS[4], wredC[4];
  int i = blockIdx.x, t = threadIdx.x;
  sd[t] = dist[i * 256 + t];
  if (t < 4) { pm[t] = posmask[i * 4 + t]; nm[t] = negmask[i * 4 + t]; }
  __syncthreads();
  bool anyp = (pm[0] | pm[1] | pm[2] | pm[3]) != 0ull;
  bool anyn = (nm[0] | nm[1] | nm[2] | nm[3]) != 0ull;
  double s = 0.0, c = 0.0;
  if (anyp && anyn) {
    for (int idx = t; idx < 65536; idx += 256) {
      int j = idx & 255, k = idx >> 8;
      if (((pm[j >> 6] >> (j & 63)) & 1ull) && ((nm[k >> 6] >> (k & 63)) & 1ull)) {
        float x = sd[j] - sd[k] + 0.2f;
        if (x > 0.f) { s += (double)x; c += 1.0; }
      }
    }
  }
  int lane = t & 63, wave = t >> 6;
  double ws = waveSumD(s), wc = waveSumD(c);
  if (lane == 0) { wredS[wave] = ws; wredC[wave] = wc; }
  __syncthreads();
  if (t == 0) {
    double ts = wredS[0] + wredS[1] + wredS[2] + wredS[3];
    double tc = wredC[0] + wredC[1] + wredC[2] + wredC[3];
    if (ts != 0.0) atomicAdd(&acc->trip_sum, ts);
    if (tc != 0.0) atomicAdd(&acc->trip_cnt, tc);
  }
}

// ---------- K9: finalize ----------
__global__ void k_final(const Accum* acc, float* out) {
  double N = (acc->total_pos > 0) ? (double)acc->total_pos : 1.0;
  out[0] = (float)(acc->loss_l / N);
  out[1] = (float)((acc->ce_pos + acc->ce_neg) / N);
  out[2] = (float)(acc->loss_p / N);
  double cnt = (acc->trip_cnt > 0.0) ? acc->trip_cnt : 1.0;
  double loss_t = acc->trip_sum / cnt;
  double npp = (acc->n_pp > 0ull) ? (double)acc->n_pp : 1.0;
  unsigned long long tot = acc->n_pp + acc->n_np;
  double denom = (tot > 0ull) ? (double)tot : 1.0;
  double Ldesk = acc->desk / npp + loss_t / denom;
  Ldesk = Ldesk / npp / 32.0;
  out[3] = (float)Ldesk;
  out[4] = (float)loss_t;
}

extern "C" void kernel_launch(void* const* d_in, const int* in_sizes, int n_in,
                              void* d_out, int out_size, void* d_ws, size_t ws_size,
                              hipStream_t stream) {
  const float* loc     = (const float*)d_in[0];
  const float* conf    = (const float*)d_in[1];
  const float* line    = (const float*)d_in[2];
  const float* pose    = (const float*)d_in[3];
  const float* dbox    = (const float*)d_in[4];
  const float* targets = (const float*)d_in[5];
  float* out = (float*)d_out;

  char* ws = (char*)d_ws;
  size_t off = 0;
  auto alloc = [&](size_t bytes) -> char* {
    char* p = ws + off;
    off += (bytes + 255) & ~(size_t)255;
    return p;
  };
  Accum* acc      = (Accum*)alloc(sizeof(Accum));              // 256 B slot
  unsigned long long* bp = (unsigned long long*)alloc(B * O * 8); // adjacent: one memset
  int*   conf_t   = (int*)  alloc((size_t)BD * 4);
  float* ce_mined = (float*)alloc((size_t)BD * 4);
  int*   posCnt   = (int*)  alloc(NCH2 * 4);
  int*   posBase  = (int*)  alloc(NCH2 * 4);
  int*   posIdx   = (int*)  alloc(256 * 4);
  float* emb      = (float*)alloc(256 * L * 4);
  float* nemb     = (float*)alloc(256 * L * 4);
  float* qp       = (float*)alloc(256 * 3 * 4);
  int*   lab      = (int*)  alloc(256 * 4);
  float* dist     = (float*)alloc(256 * 256 * 4);
  unsigned long long* posmask = (unsigned long long*)alloc(256 * 4 * 8);
  unsigned long long* negmask = (unsigned long long*)alloc(256 * 4 * 8);

  hipMemsetAsync(acc, 0, 256 + B * O * 8, stream);   // acc + bp
  k_bestprior<<<dim3(NBX, B), 256, 0, stream>>>(dbox, targets, bp);
  k_losses  <<<dim3(NBX, B), 256, 0, stream>>>(loc, conf, pose, dbox, targets, bp,
                                               conf_t, ce_mined, posCnt, acc);
  k_topk    <<<B, 1024, 0, stream>>>(ce_mined, acc);
  k_selscan <<<1, 1024, 0, stream>>>(posCnt, posBase, acc);
  k_selwrite<<<NCH2, 256, 0, stream>>>(conf_t, posBase, posIdx);
  k_gather  <<<1, 256, 0, stream>>>(line, targets, conf_t, bp, dbox, posIdx, acc,
                                    emb, nemb, qp, lab);
  k_pairs   <<<256, 256, 0, stream>>>(emb, nemb, qp, lab, acc, dist, posmask, negmask);
  k_trip    <<<256, 256, 0, stream>>>(dist, posmask, negmask, acc);
  k_final   <<<1, 1, 0, stream>>>(acc, out);
}

// Round 4
// 205.809 us; speedup vs baseline: 1.4131x; 1.0116x over previous
//
#include <hip/hip_runtime.h>
#include <hip/hip_bf16.h>
#include <cstdint>

#define B 32
#define D 8732
#define C 21
#define L 32
#define O 8
#define BD (B*D)
#define NBX 35                 // ceil(8732/256)
#define NCH2 (NBX*B)           // 1120 chunks of 256 (flat order: b-major, d-minor)

struct Accum {
  double loss_l, loss_p, ce_pos, ce_neg, desk, trip_sum, trip_cnt;
  unsigned long long n_pp, n_np;
  int num_pos[B];
  int total_pos;
  int Pc;
};

__device__ inline double waveSumD(double v) {
  #pragma unroll
  for (int s = 32; s > 0; s >>= 1) v += __shfl_down(v, s, 64);
  return v;
}

__device__ inline float iou_one(float tx1, float ty1, float tx2, float ty2, float ta,
                                float px1, float py1, float px2, float py2, float areaB) {
  float lx = fmaxf(tx1, px1), ly = fmaxf(ty1, py1);
  float rx = fminf(tx2, px2), ry = fminf(ty2, py2);
  float iw = fmaxf(rx - lx, 0.f), ih = fmaxf(ry - ly, 0.f);
  float inter = iw * ih;
  return inter / (ta + areaB - inter);
}

// ---------- K1: per-(b,t) best prior via packed atomicMax ----------
__global__ __launch_bounds__(256, 4) void k_bestprior(const float* __restrict__ dbox,
                            const float* __restrict__ targets,
                            unsigned long long* __restrict__ bp) {
  int b = blockIdx.y;
  int d0 = blockIdx.x * 256;
  int tid = threadIdx.x;
  __shared__ float tb[O][4];
  __shared__ float ta[O];
  __shared__ unsigned long long wm[4][O];
  if (tid < O) {
    const float* tr = targets + ((size_t)b * O + tid) * 9;
    tb[tid][0] = tr[0]; tb[tid][1] = tr[1]; tb[tid][2] = tr[2]; tb[tid][3] = tr[3];
    ta[tid] = (tr[2] - tr[0]) * (tr[3] - tr[1]);
  }
  __syncthreads();
  int d = d0 + tid;
  unsigned long long key[O];
  if (d < D) {
    float4 db = *(const float4*)(dbox + (size_t)d * 4);
    float px1 = db.x - 0.5f*db.z, py1 = db.y - 0.5f*db.w;
    float px2 = db.x + 0.5f*db.z, py2 = db.y + 0.5f*db.w;
    float areaB = db.z * db.w;
    #pragma unroll
    for (int t = 0; t < O; t++) {
      float iou = iou_one(tb[t][0], tb[t][1], tb[t][2], tb[t][3], ta[t],
                          px1, py1, px2, py2, areaB);
      key[t] = ((unsigned long long)__float_as_uint(iou) << 32)
             | (unsigned long long)(0xFFFFFFFFu - (unsigned)d);   // tie -> smaller d
    }
  } else {
    #pragma unroll
    for (int t = 0; t < O; t++) key[t] = 0ull;
  }
  int lane = tid & 63, wav = tid >> 6;
  #pragma unroll
  for (int t = 0; t < O; t++) {
    unsigned long long k = key[t];
    #pragma unroll
    for (int s = 32; s > 0; s >>= 1) {
      unsigned long long o = __shfl_down(k, s, 64);
      if (o > k) k = o;
    }
    if (lane == 0) wm[wav][t] = k;
  }
  __syncthreads();
  if (tid < O) {
    unsigned long long k = wm[0][tid];
    #pragma unroll
    for (int w = 1; w < 4; w++) if (wm[w][tid] > k) k = wm[w][tid];
    atomicMax(&bp[b * O + tid], k);
  }
}

// ---------- K2: conf_t, ce, loc/pose losses, fused pos counts ----------
__global__ __launch_bounds__(256, 4) void k_losses(const float* __restrict__ loc,
                         const float* __restrict__ conf,
                         const float* __restrict__ pose, const float* __restrict__ dbox,
                         const float* __restrict__ targets,
                         const unsigned long long* __restrict__ bp,
                         int* __restrict__ conf_t, float* __restrict__ ce_mined,
                         int* __restrict__ posCnt, Accum* acc) {
  __shared__ __align__(16) float sconf[256 * C];
  __shared__ float tb[O][4], ta[O], tl[O], tp_[O][3];
  __shared__ int bpd[O];
  __shared__ double wred[4][3];
  __shared__ int swp[4];
  int b = blockIdx.y;
  int d0 = blockIdx.x * 256;
  int tid = threadIdx.x;
  int nd = D - d0; if (nd > 256) nd = 256;
  if (tid < O) {
    const float* tr = targets + ((size_t)b * O + tid) * 9;
    tb[tid][0] = tr[0]; tb[tid][1] = tr[1]; tb[tid][2] = tr[2]; tb[tid][3] = tr[3];
    ta[tid] = (tr[2] - tr[0]) * (tr[3] - tr[1]);
    tl[tid] = tr[4];
    tp_[tid][0] = tr[5]; tp_[tid][1] = tr[6]; tp_[tid][2] = tr[7];
  }
  if (tid >= 64 && tid < 64 + O) {
    unsigned long long k = bp[b * O + (tid - 64)];
    bpd[tid - 64] = (int)(0xFFFFFFFFu - (unsigned)(k & 0xFFFFFFFFull));
  }
  const float* cbase = conf + ((size_t)b * D + d0) * C;
  int nf4 = nd * C / 4;                      // 256*21 and 28*21 both divisible by 4
  for (int i = tid; i < nf4; i += 256)
    ((float4*)sconf)[i] = ((const float4*)cbase)[i];
  __syncthreads();
  int d = d0 + tid;
  double ll = 0, lp = 0, cp = 0;
  int cls = -1;
  if (d < D) {
    size_t bd = (size_t)b * D + d;
    float4 db = *(const float4*)(dbox + (size_t)d * 4);
    float px1 = db.x - 0.5f*db.z, py1 = db.y - 0.5f*db.w;
    float px2 = db.x + 0.5f*db.z, py2 = db.y + 0.5f*db.w;
    float areaB = db.z * db.w;
    float bv = -1.0f; int bi = 0;
    #pragma unroll
    for (int t = 0; t < O; t++) {
      float iou = iou_one(tb[t][0], tb[t][1], tb[t][2], tb[t][3], ta[t],
                          px1, py1, px2, py2, areaB);
      if (iou > bv) { bv = iou; bi = t; }    // argmax over truths: first max wins
    }
    #pragma unroll
    for (int t = O - 1; t >= 0; t--)         // numpy scatter: last truth wins
      if (bpd[t] == d) { bi = t; bv = 2.0f; break; }
    cls = (bv < 0.5f) ? 0 : ((int)tl[bi] + 1);
    conf_t[bd] = cls;
    // conf row -> registers (static indices only; x[cls] read from LDS to
    // avoid dynamic register indexing -> scratch)
    float x[C];
    #pragma unroll
    for (int c = 0; c < C; c++) x[c] = sconf[tid * C + c];
    float m = x[0];
    #pragma unroll
    for (int c = 1; c < C; c++) m = fmaxf(m, x[c]);
    float s = 0.f;
    #pragma unroll
    for (int c = 0; c < C; c++) s += __expf(x[c] - m);
    float xc = sconf[tid * C + cls];
    float ce = m + __logf(s) - xc;
    if (cls > 0) {
      cp = ce;
      ce_mined[bd] = 0.f;
      float g0 = ((tb[bi][0] + tb[bi][2]) * 0.5f - db.x) / (0.1f * db.z);
      float g1 = ((tb[bi][1] + tb[bi][3]) * 0.5f - db.y) / (0.1f * db.w);
      float g2 = logf((tb[bi][2] - tb[bi][0]) / db.z) / 0.2f;
      float g3 = logf((tb[bi][3] - tb[bi][1]) / db.w) / 0.2f;
      float4 lo = *(const float4*)(loc + bd * 4);
      float dv, a;
      dv = lo.x - g0; a = fabsf(dv); ll += (double)((a < 1.f) ? 0.5f*dv*dv : a - 0.5f);
      dv = lo.y - g1; a = fabsf(dv); ll += (double)((a < 1.f) ? 0.5f*dv*dv : a - 0.5f);
      dv = lo.z - g2; a = fabsf(dv); ll += (double)((a < 1.f) ? 0.5f*dv*dv : a - 0.5f);
      dv = lo.w - g3; a = fabsf(dv); ll += (double)((a < 1.f) ? 0.5f*dv*dv : a - 0.5f);
      const float* po = pose + bd * 3;
      #pragma unroll
      for (int q = 0; q < 3; q++) {
        float pd = po[q] - tp_[bi][q];
        lp += (double)pd * (double)pd;
      }
    } else {
      ce_mined[bd] = fmaxf(ce, 0.f);
    }
  }
  bool p = (cls > 0);
  unsigned long long pm = __ballot(p);
  int lane = tid & 63, wav = tid >> 6;
  double a0 = waveSumD(ll), a1 = waveSumD(lp), a2 = waveSumD(cp);
  if (lane == 0) {
    wred[wav][0] = a0; wred[wav][1] = a1; wred[wav][2] = a2;
    swp[wav] = __popcll(pm);
  }
  __syncthreads();
  if (tid == 0) {
    double tll = wred[0][0] + wred[1][0] + wred[2][0] + wred[3][0];
    double tlp = wred[0][1] + wred[1][1] + wred[2][1] + wred[3][1];
    double tcp = wred[0][2] + wred[1][2] + wred[2][2] + wred[3][2];
    int pc = swp[0] + swp[1] + swp[2] + swp[3];
    posCnt[b * NBX + blockIdx.x] = pc;
    if (tll != 0.0) atomicAdd(&acc->loss_l, tll);
    if (tlp != 0.0) atomicAdd(&acc->loss_p, tlp);
    if (tcp != 0.0) atomicAdd(&acc->ce_pos, tcp);
    if (pc) { atomicAdd(&acc->num_pos[b], pc); atomicAdd(&acc->total_pos, pc); }
  }
}

// ---------- K3: per-batch top-k negative CE sum (LDS-staged radix select) ----------
__global__ __launch_bounds__(1024, 4) void k_topk(const float* __restrict__ ce_mined, Accum* acc) {
  int b = blockIdx.x;
  int tid = threadIdx.x;
  int lane = tid & 63, wav = tid >> 6;
  __shared__ __align__(16) float sce[D];
  __shared__ int whist[16][256];
  __shared__ int hist[256];
  __shared__ unsigned int sh_prefix;
  __shared__ int sh_k;
  __shared__ double wsum[16], wcnt[16];
  const float* ce = ce_mined + (size_t)b * D;
  for (int i = tid; i < D / 4; i += 1024)
    ((float4*)sce)[i] = ((const float4*)ce)[i];      // 8732 % 4 == 0
  int k = acc->num_pos[b] * 3;
  if (k > D) k = D;
  __syncthreads();
  unsigned int prefix = 0; int kk = k;   // kk >= 1 (num_pos >= 1 always)
  for (int pass = 0; pass < 4; pass++) {
    int shift = 24 - 8 * pass;
    for (int i = tid; i < 16 * 256; i += 1024) ((int*)whist)[i] = 0;
    __syncthreads();
    unsigned int himask = (pass == 0) ? 0u : (0xFFFFFFFFu << (shift + 8));
    for (int d = tid; d < D; d += 1024) {
      unsigned int key = __float_as_uint(sce[d]);
      if ((key & himask) == (prefix & himask))
        atomicAdd(&whist[wav][(key >> shift) & 255], 1);
    }
    __syncthreads();
    if (tid < 256) {
      int h = 0;
      #pragma unroll
      for (int w = 0; w < 16; w++) h += whist[w][tid];
      hist[tid] = h;
    }
    __syncthreads();
    if (tid < 64) {
      int l = tid;
      int h0 = hist[l*4], h1 = hist[l*4+1], h2 = hist[l*4+2], h3 = hist[l*4+3];
      int loc4 = h0 + h1 + h2 + h3;
      int suf = loc4;
      #pragma unroll
      for (int s = 1; s < 64; s <<= 1) {
        int o = __shfl_down(suf, s, 64);
        if (l + s < 64) suf += o;
      }
      int snext = suf - loc4;
      int s3 = snext + h3, s2 = s3 + h2, s1 = s2 + h1, s0 = s1 + h0;
      if (s3 >= kk && snext < kk) { sh_prefix = prefix | ((unsigned)(l*4+3) << shift); sh_k = kk - snext; }
      if (s2 >= kk && s3 < kk)    { sh_prefix = prefix | ((unsigned)(l*4+2) << shift); sh_k = kk - s3; }
      if (s1 >= kk && s2 < kk)    { sh_prefix = prefix | ((unsigned)(l*4+1) << shift); sh_k = kk - s2; }
      if (s0 >= kk && s1 < kk)    { sh_prefix = prefix | ((unsigned)(l*4+0) << shift); sh_k = kk - s1; }
    }
    __syncthreads();
    prefix = sh_prefix; kk = sh_k;
    __syncthreads();
  }
  float T = __uint_as_float(prefix);
  double sgt = 0.0; int cgt = 0;
  for (int d = tid; d < D; d += 1024) {
    float v = sce[d];
    if (__float_as_uint(v) > prefix) { sgt += (double)v; cgt++; }
  }
  double wv = waveSumD(sgt);
  double wc = waveSumD((double)cgt);
  if (lane == 0) { wsum[wav] = wv; wcnt[wav] = wc; }
  __syncthreads();
  if (tid == 0) {
    double tsg = 0, tcg = 0;
    #pragma unroll
    for (int w = 0; w < 16; w++) { tsg += wsum[w]; tcg += wcnt[w]; }
    atomicAdd(&acc->ce_neg, tsg + ((double)k - tcg) * (double)T);
  }
}

// ---------- K4: parallel exclusive scan of per-chunk positive counts ----------
__global__ __launch_bounds__(1024) void k_selscan(const int* __restrict__ posCnt,
                                                  int* __restrict__ posBase, Accum* acc) {
  __shared__ int sp[2048];
  int tid = threadIdx.x;
  for (int i = tid; i < 2048; i += 1024) sp[i] = (i < NCH2) ? posCnt[i] : 0;
  __syncthreads();
  for (int s = 1; s < 2048; s <<= 1) {
    int i0 = tid, i1 = tid + 1024;
    int v0 = sp[i0] + ((i0 >= s) ? sp[i0 - s] : 0);
    int v1 = sp[i1] + ((i1 >= s) ? sp[i1 - s] : 0);
    __syncthreads();
    sp[i0] = v0; sp[i1] = v1;
    __syncthreads();
  }
  for (int i = tid; i < NCH2; i += 1024) posBase[i] = sp[i] - posCnt[i];  // exclusive
  if (tid == 0) {
    int tp = acc->total_pos;
    acc->Pc = (tp < 256) ? tp : 256;
  }
}

// ---------- K5: write first-256 positive flat indices (stable) ----------
__global__ __launch_bounds__(256, 4) void k_selwrite(const int* __restrict__ conf_t,
                           const int* __restrict__ posBase,
                           int* __restrict__ posIdx) {
  int ch = blockIdx.x;
  int pbase = posBase[ch];
  if (pbase >= 256) return;
  int b = ch / NBX, cx = ch - b * NBX;
  int dd = cx * 256 + threadIdx.x;
  int i = b * D + dd;
  bool p = (dd < D) && (conf_t[i] > 0);
  unsigned long long pm = __ballot(p);
  int lane = threadIdx.x & 63, wave = threadIdx.x >> 6;
  __shared__ int wp[4];
  if (lane == 0) wp[wave] = __popcll(pm);
  __syncthreads();
  int pb = pbase;
  for (int w = 0; w < wave; w++) pb += wp[w];
  unsigned long long lt = (lane == 0) ? 0ull : (~0ull >> (64 - lane));
  int prank = pb + __popcll(pm & lt);
  if (p && prank < 256) posIdx[prank] = i;
}

// ---------- K6: gather embeddings / labels / poses for the Pc positives ----------
__global__ __launch_bounds__(256, 4) void k_gather(const float* __restrict__ line,
                         const float* __restrict__ targets,
                         const int* __restrict__ conf_t, const unsigned long long* __restrict__ bp,
                         const float* __restrict__ dbox, const int* __restrict__ posIdx,
                         const Accum* acc, float* __restrict__ emb, float* __restrict__ nemb,
                         float* __restrict__ qp, int* __restrict__ lab) {
  __shared__ float st[B * O * 9];      // 9216 B: all targets
  __shared__ int sbp[B * O];
  int g = threadIdx.x;
  for (int i = g; i < B * O * 9; i += 256) st[i] = targets[i];
  {
    unsigned long long k = bp[g];      // 256 entries exactly
    sbp[g] = (int)(0xFFFFFFFFu - (unsigned)(k & 0xFFFFFFFFull));
  }
  __syncthreads();
  int Pc = acc->Pc;
  if (g >= Pc) return;                 // invalid rows never contribute (masked by Pc)
  int flat = posIdx[g];
  int b = flat / D, d = flat - b * D;
  float4 db = *(const float4*)(dbox + (size_t)d * 4);
  float px1 = db.x - 0.5f*db.z, py1 = db.y - 0.5f*db.w;
  float px2 = db.x + 0.5f*db.z, py2 = db.y + 0.5f*db.w;
  float areaB = db.z * db.w;
  float bv = -1.0f; int bi = 0;
  #pragma unroll
  for (int t = 0; t < O; t++) {
    const float* tr = st + (b * O + t) * 9;
    float ta = (tr[2] - tr[0]) * (tr[3] - tr[1]);
    float iou = iou_one(tr[0], tr[1], tr[2], tr[3], ta, px1, py1, px2, py2, areaB);
    if (iou > bv) { bv = iou; bi = t; }
  }
  #pragma unroll
  for (int t = O - 1; t >= 0; t--)
    if (sbp[b * O + t] == d) { bi = t; break; }
  const float4* e4 = (const float4*)(line + (size_t)flat * L);
  float4* o4 = (float4*)(emb + g * L);
  float4* n4 = (float4*)(nemb + g * L);
  float4 v[8];
  float nrm2 = 0.f;
  #pragma unroll
  for (int c = 0; c < 8; c++) {
    v[c] = e4[c];
    o4[c] = v[c];
    nrm2 += v[c].x*v[c].x + v[c].y*v[c].y + v[c].z*v[c].z + v[c].w*v[c].w;
  }
  float inv = 1.f / fmaxf(sqrtf(nrm2), 1e-12f);
  #pragma unroll
  for (int c = 0; c < 8; c++) {
    float4 t = v[c];
    t.x *= inv; t.y *= inv; t.z *= inv; t.w *= inv;
    n4[c] = t;
  }
  lab[g] = conf_t[flat];
  const float* tr = st + (b * O + bi) * 9;
  qp[g * 3 + 0] = tr[5]; qp[g * 3 + 1] = tr[6]; qp[g * 3 + 2] = tr[7];
}

// ---------- K7: pairwise dist / masks / desk ----------
__global__ __launch_bounds__(256, 4) void k_pairs(const float* __restrict__ emb,
                        const float* __restrict__ nemb,
                        const float* __restrict__ qp, const int* __restrict__ lab,
                        Accum* acc, float* __restrict__ dist,
                        unsigned long long* __restrict__ posmask,
                        unsigned long long* __restrict__ negmask) {
  __shared__ float ei[L], ni[L], qi[3];
  __shared__ int li, Pc_s;
  __shared__ double wred[4];
  int i = blockIdx.x, j = threadIdx.x;
  if (j < L) { ei[j] = emb[i * L + j]; ni[j] = nemb[i * L + j]; }
  if (j < 3) qi[j] = qp[i * 3 + j];
  if (j == 0) { li = lab[i]; Pc_s = acc->Pc; }
  __syncthreads();
  int Pc = Pc_s;
  bool vi = (i < Pc), vj = (j < Pc);
  const float4* nj4 = (const float4*)(nemb + j * L);
  const float4* ej4 = (const float4*)(emb + j * L);
  float sq = 0.f, esq = 0.f;
  #pragma unroll
  for (int c = 0; c < 8; c++) {
    float4 nn = nj4[c], ee = ej4[c];
    float d0 = ni[c*4+0] - nn.x, d1 = ni[c*4+1] - nn.y, d2 = ni[c*4+2] - nn.z, d3 = ni[c*4+3] - nn.w;
    sq += d0*d0 + d1*d1 + d2*d2 + d3*d3;
    float e0 = ei[c*4+0] - ee.x, e1 = ei[c*4+1] - ee.y, e2 = ei[c*4+2] - ee.z, e3 = ei[c*4+3] - ee.w;
    esq += e0*e0 + e1*e1 + e2*e2 + e3*e3;
  }
  float dd = sqrtf(fmaxf(sq, 1e-12f));
  dist[i * 256 + j] = dd;
  float qsq = 0.f;
  #pragma unroll
  for (int c = 0; c < 3; c++) { float dq = qi[c] - qp[j * 3 + c]; qsq += dq * dq; }
  bool vp = vi && vj && (i != j);
  bool same = (li == lab[j]);
  bool pp = vp && same && (dd > 0.2f);
  bool np = vp && !same && (dd < 0.8f);
  unsigned long long pb = __ballot(pp), nb = __ballot(np);
  int lane = j & 63, wave = j >> 6;
  if (lane == 0) {
    posmask[i * 4 + wave] = pb;
    negmask[i * 4 + wave] = nb;
    if (pb) atomicAdd(&acc->n_pp, (unsigned long long)__popcll(pb));
    if (nb) atomicAdd(&acc->n_np, (unsigned long long)__popcll(nb));
  }
  float diff = esq - qsq;
  double dsk = pp ? (double)diff * (double)diff : 0.0;
  double w = waveSumD(dsk);
  if (lane == 0) wred[wave] = w;
  __syncthreads();
  if (j == 0) {
    double t = wred[0] + wred[1] + wred[2] + wred[3];
    if (t != 0.0) atomicAdd(&acc->desk, t);
  }
}

// ---------- K8: triple loop ----------
__global__ __launch_bounds__(256, 4) void k_trip(const float* __restrict__ dist,
                       const unsigned long long* __restrict__ posmask,
                       const unsigned long long* __restrict__ negmask, Accum* acc) {
  __shared__ float sd[256];
  __shared__ unsigned long long pm[4], nm[4];
  __shared__ double wredS[4], wredC[4];
  int i = blockIdx.x, t = threadIdx.x;
  sd[t] = dist[i * 256 + t];
  if (t < 4) { pm[t] = posmask[i * 4 + t]; nm[t] = negmask[i * 4 + t]; }
  __syncthreads();
  bool anyp = (pm[0] | pm[1] | pm[2] | pm[3]) != 0ull;
  bool anyn = (nm[0] | nm[1] | nm[2] | nm[3]) != 0ull;
  double s = 0.0, c = 0.0;
  if (anyp && anyn) {
    for (int idx = t; idx < 65536; idx += 256) {
      int j = idx & 255, k = idx >> 8;
      if (((pm[j >> 6] >> (j & 63)) & 1ull) && ((nm[k >> 6] >> (k & 63)) & 1ull)) {
        float x = sd[j] - sd[k] + 0.2f;
        if (x > 0.f) { s += (double)x; c += 1.0; }
      }
    }
  }
  int lane = t & 63, wave = t >> 6;
  double ws = waveSumD(s), wc = waveSumD(c);
  if (lane == 0) { wredS[wave] = ws; wredC[wave] = wc; }
  __syncthreads();
  if (t == 0) {
    double ts = wredS[0] + wredS[1] + wredS[2] + wredS[3];
    double tc = wredC[0] + wredC[1] + wredC[2] + wredC[3];
    if (ts != 0.0) atomicAdd(&acc->trip_sum, ts);
    if (tc != 0.0) atomicAdd(&acc->trip_cnt, tc);
  }
}

// ---------- K9: finalize ----------
__global__ void k_final(const Accum* acc, float* out) {
  double N = (acc->total_pos > 0) ? (double)acc->total_pos : 1.0;
  out[0] = (float)(acc->loss_l / N);
  out[1] = (float)((acc->ce_pos + acc->ce_neg) / N);
  out[2] = (float)(acc->loss_p / N);
  double cnt = (acc->trip_cnt > 0.0) ? acc->trip_cnt : 1.0;
  double loss_t = acc->trip_sum / cnt;
  double npp = (acc->n_pp > 0ull) ? (double)acc->n_pp : 1.0;
  unsigned long long tot = acc->n_pp + acc->n_np;
  double denom = (tot > 0ull) ? (double)tot : 1.0;
  double Ldesk = acc->desk / npp + loss_t / denom;
  Ldesk = Ldesk / npp / 32.0;
  out[3] = (float)Ldesk;
  out[4] = (float)loss_t;
}

extern "C" void kernel_launch(void* const* d_in, const int* in_sizes, int n_in,
                              void* d_out, int out_size, void* d_ws, size_t ws_size,
                              hipStream_t stream) {
  const float* loc     = (const float*)d_in[0];
  const float* conf    = (const float*)d_in[1];
  const float* line    = (const float*)d_in[2];
  const float* pose    = (const float*)d_in[3];
  const float* dbox    = (const float*)d_in[4];
  const float* targets = (const float*)d_in[5];
  float* out = (float*)d_out;

  char* ws = (char*)d_ws;
  size_t off = 0;
  auto alloc = [&](size_t bytes) -> char* {
    char* p = ws + off;
    off += (bytes + 255) & ~(size_t)255;
    return p;
  };
  Accum* acc      = (Accum*)alloc(sizeof(Accum));              // 256 B slot
  unsigned long long* bp = (unsigned long long*)alloc(B * O * 8); // adjacent: one memset
  int*   conf_t   = (int*)  alloc((size_t)BD * 4);
  float* ce_mined = (float*)alloc((size_t)BD * 4);
  int*   posCnt   = (int*)  alloc(NCH2 * 4);
  int*   posBase  = (int*)  alloc(NCH2 * 4);
  int*   posIdx   = (int*)  alloc(256 * 4);
  float* emb      = (float*)alloc(256 * L * 4);
  float* nemb     = (float*)alloc(256 * L * 4);
  float* qp       = (float*)alloc(256 * 3 * 4);
  int*   lab      = (int*)  alloc(256 * 4);
  float* dist     = (float*)alloc(256 * 256 * 4);
  unsigned long long* posmask = (unsigned long long*)alloc(256 * 4 * 8);
  unsigned long long* negmask = (unsigned long long*)alloc(256 * 4 * 8);

  hipMemsetAsync(acc, 0, 256 + B * O * 8, stream);   // acc + bp
  k_bestprior<<<dim3(NBX, B), 256, 0, stream>>>(dbox, targets, bp);
  k_losses  <<<dim3(NBX, B), 256, 0, stream>>>(loc, conf, pose, dbox, targets, bp,
                                               conf_t, ce_mined, posCnt, acc);
  k_topk    <<<B, 1024, 0, stream>>>(ce_mined, acc);
  k_selscan <<<1, 1024, 0, stream>>>(posCnt, posBase, acc);
  k_selwrite<<<NCH2, 256, 0, stream>>>(conf_t, posBase, posIdx);
  k_gather  <<<1, 256, 0, stream>>>(line, targets, conf_t, bp, dbox, posIdx, acc,
                                    emb, nemb, qp, lab);
  k_pairs   <<<256, 256, 0, stream>>>(emb, nemb, qp, lab, acc, dist, posmask, negmask);
  k_trip    <<<256, 256, 0, stream>>>(dist, posmask, negmask, acc);
  k_final   <<<1, 1, 0, stream>>>(acc, out);
}

// Round 5
// 197.732 us; speedup vs baseline: 1.4709x; 1.0408x over previous
//
#include <hip/hip_runtime.h>
#include <hip/hip_bf16.h>
#include <cstdint>

#define B 32
#define D 8732
#define C 21
#define L 32
#define O 8
#define NW 273   // ceil(D/32) bitmask words

struct Accum {
  double loss_l, loss_p, ce_pos, ce_neg, desk, trip_sum, trip_cnt;
  unsigned long long n_pp, n_np;
  int total_pos;
  int Pc;
};

__device__ inline double waveSumD(double v) {
  #pragma unroll
  for (int s = 32; s > 0; s >>= 1) v += __shfl_down(v, s, 64);
  return v;
}

__device__ inline float iou_one(float tx1, float ty1, float tx2, float ty2, float ta,
                                float px1, float py1, float px2, float py2, float areaB) {
  float lx = fmaxf(tx1, px1), ly = fmaxf(ty1, py1);
  float rx = fminf(tx2, px2), ry = fminf(ty2, py2);
  float iw = fmaxf(rx - lx, 0.f), ih = fmaxf(ry - ly, 0.f);
  float inter = iw * ih;
  return inter / (ta + areaB - inter);
}

// ============ K1: fully fused per-batch kernel ============
// one block (1024 thr) per batch: best-prior match -> conf_t/ce/loc/pose losses
// -> ce_mined in LDS -> radix top-k negative sum -> stable positive compaction.
// No global intermediates except packed positive list.
__global__ __launch_bounds__(1024) void k_fused(
    const float* __restrict__ loc, const float* __restrict__ conf,
    const float* __restrict__ pose, const float* __restrict__ dbox,
    const float* __restrict__ targets,
    int* __restrict__ posBuf, int* __restrict__ posCnt, Accum* acc)
{
  int b = blockIdx.x;
  int tid = threadIdx.x;
  int lane = tid & 63, wav = tid >> 6;
  __shared__ __align__(16) float sce[D];        // 34928 B
  __shared__ int whist[16][256];                // 16384 B
  __shared__ int hist[256];
  __shared__ int sp[512];                       // scan buffer
  __shared__ unsigned pbits[NW];                // positive bitmask
  __shared__ float tb[O][4], ta[O], tl[O], tp_[O][3];
  __shared__ int bpd[O];
  __shared__ unsigned long long wm[16][O];
  __shared__ double wred[16][3];
  __shared__ unsigned sh_prefix;
  __shared__ int sh_k;
  __shared__ double wsum[16], wcnt[16];

  if (tid < O) {
    const float* tr = targets + ((size_t)b * O + tid) * 9;
    tb[tid][0] = tr[0]; tb[tid][1] = tr[1]; tb[tid][2] = tr[2]; tb[tid][3] = tr[3];
    ta[tid] = (tr[2] - tr[0]) * (tr[3] - tr[1]);
    tl[tid] = tr[4];
    tp_[tid][0] = tr[5]; tp_[tid][1] = tr[6]; tp_[tid][2] = tr[7];
  }
  for (int i = tid; i < NW; i += 1024) pbits[i] = 0;
  __syncthreads();

  // ---- phase 1: per-truth best prior (argmax over d, tie -> smaller d) ----
  unsigned long long key[O];
  #pragma unroll
  for (int t = 0; t < O; t++) key[t] = 0ull;
  for (int d = tid; d < D; d += 1024) {
    float4 db = *(const float4*)(dbox + (size_t)d * 4);
    float px1 = db.x - 0.5f*db.z, py1 = db.y - 0.5f*db.w;
    float px2 = db.x + 0.5f*db.z, py2 = db.y + 0.5f*db.w;
    float areaB = db.z * db.w;
    #pragma unroll
    for (int t = 0; t < O; t++) {
      float iou = iou_one(tb[t][0], tb[t][1], tb[t][2], tb[t][3], ta[t],
                          px1, py1, px2, py2, areaB);
      unsigned long long kk = ((unsigned long long)__float_as_uint(iou) << 32)
                            | (unsigned long long)(0xFFFFFFFFu - (unsigned)d);
      if (kk > key[t]) key[t] = kk;
    }
  }
  #pragma unroll
  for (int t = 0; t < O; t++) {
    unsigned long long k = key[t];
    #pragma unroll
    for (int s = 32; s > 0; s >>= 1) {
      unsigned long long o = __shfl_down(k, s, 64);
      if (o > k) k = o;
    }
    if (lane == 0) wm[wav][t] = k;
  }
  __syncthreads();
  if (tid < O) {
    unsigned long long k = wm[0][tid];
    #pragma unroll
    for (int w = 1; w < 16; w++) if (wm[w][tid] > k) k = wm[w][tid];
    bpd[tid] = (int)(0xFFFFFFFFu - (unsigned)(k & 0xFFFFFFFFull));
  }
  __syncthreads();

  // ---- phase 2: per-prior class, ce, loc/pose losses; sce + pbits in LDS ----
  double ll = 0, lp = 0, cp = 0;
  for (int d = tid; d < D; d += 1024) {
    float4 db = *(const float4*)(dbox + (size_t)d * 4);
    float px1 = db.x - 0.5f*db.z, py1 = db.y - 0.5f*db.w;
    float px2 = db.x + 0.5f*db.z, py2 = db.y + 0.5f*db.w;
    float areaB = db.z * db.w;
    float bv = -1.0f; int bi = 0;
    #pragma unroll
    for (int t = 0; t < O; t++) {
      float iou = iou_one(tb[t][0], tb[t][1], tb[t][2], tb[t][3], ta[t],
                          px1, py1, px2, py2, areaB);
      if (iou > bv) { bv = iou; bi = t; }     // first max wins (argmax axis=0)
    }
    #pragma unroll
    for (int t = O - 1; t >= 0; t--)          // numpy scatter: last truth wins
      if (bpd[t] == d) { bi = t; bv = 2.0f; break; }
    int cls = (bv < 0.5f) ? 0 : ((int)tl[bi] + 1);
    const float* cb = conf + ((size_t)b * D + d) * C;
    float x[C];
    #pragma unroll
    for (int c = 0; c < C; c++) x[c] = cb[c];
    float m = x[0];
    #pragma unroll
    for (int c = 1; c < C; c++) m = fmaxf(m, x[c]);
    float s = 0.f;
    #pragma unroll
    for (int c = 0; c < C; c++) s += __expf(x[c] - m);
    float xc = cb[cls];                       // L1-hot reread, avoids dyn reg idx
    float ce = m + __logf(s) - xc;
    if (cls > 0) {
      cp += ce;
      sce[d] = 0.f;
      atomicOr(&pbits[d >> 5], 1u << (d & 31));
      float g0 = ((tb[bi][0] + tb[bi][2]) * 0.5f - db.x) / (0.1f * db.z);
      float g1 = ((tb[bi][1] + tb[bi][3]) * 0.5f - db.y) / (0.1f * db.w);
      float g2 = logf((tb[bi][2] - tb[bi][0]) / db.z) / 0.2f;
      float g3 = logf((tb[bi][3] - tb[bi][1]) / db.w) / 0.2f;
      size_t bd = (size_t)b * D + d;
      float4 lo = *(const float4*)(loc + bd * 4);
      float dv, a;
      dv = lo.x - g0; a = fabsf(dv); ll += (double)((a < 1.f) ? 0.5f*dv*dv : a - 0.5f);
      dv = lo.y - g1; a = fabsf(dv); ll += (double)((a < 1.f) ? 0.5f*dv*dv : a - 0.5f);
      dv = lo.z - g2; a = fabsf(dv); ll += (double)((a < 1.f) ? 0.5f*dv*dv : a - 0.5f);
      dv = lo.w - g3; a = fabsf(dv); ll += (double)((a < 1.f) ? 0.5f*dv*dv : a - 0.5f);
      const float* po = pose + bd * 3;
      #pragma unroll
      for (int q = 0; q < 3; q++) {
        float pd = po[q] - tp_[bi][q];
        lp += (double)pd * (double)pd;
      }
    } else {
      sce[d] = fmaxf(ce, 0.f);
    }
  }
  double a0 = waveSumD(ll), a1 = waveSumD(lp), a2 = waveSumD(cp);
  if (lane == 0) { wred[wav][0] = a0; wred[wav][1] = a1; wred[wav][2] = a2; }
  __syncthreads();
  if (tid == 0) {
    double tll = 0, tlp = 0, tcp = 0;
    #pragma unroll
    for (int w = 0; w < 16; w++) { tll += wred[w][0]; tlp += wred[w][1]; tcp += wred[w][2]; }
    if (tll != 0.0) atomicAdd(&acc->loss_l, tll);
    if (tlp != 0.0) atomicAdd(&acc->loss_p, tlp);
    if (tcp != 0.0) atomicAdd(&acc->ce_pos, tcp);
  }

  // ---- phase 3: scan positive-bitmask popcounts; stable compaction ----
  if (tid < 512) sp[tid] = (tid < NW) ? (int)__popc(pbits[tid]) : 0;
  __syncthreads();
  for (int s = 1; s < 512; s <<= 1) {
    int v = 0;
    if (tid < 512) v = sp[tid] + ((tid >= s) ? sp[tid - s] : 0);
    __syncthreads();
    if (tid < 512) sp[tid] = v;
    __syncthreads();
  }
  int npos = sp[NW - 1];
  if (tid == 0) {
    posCnt[b] = (npos < 256) ? npos : 256;
    atomicAdd(&acc->total_pos, npos);
  }
  if (tid < NW) {
    unsigned w = pbits[tid];
    int base = sp[tid] - (int)__popc(w);     // exclusive prefix
    while (w) {
      int j = __ffs(w) - 1; w &= w - 1;
      int d = tid * 32 + j;
      int rank = base++;
      if (rank < 256) {
        // recompute (cls, bi) for this positive — identical arithmetic to phase 2
        float4 db = *(const float4*)(dbox + (size_t)d * 4);
        float px1 = db.x - 0.5f*db.z, py1 = db.y - 0.5f*db.w;
        float px2 = db.x + 0.5f*db.z, py2 = db.y + 0.5f*db.w;
        float areaB = db.z * db.w;
        float bv = -1.0f; int bi = 0;
        #pragma unroll
        for (int t = 0; t < O; t++) {
          float iou = iou_one(tb[t][0], tb[t][1], tb[t][2], tb[t][3], ta[t],
                              px1, py1, px2, py2, areaB);
          if (iou > bv) { bv = iou; bi = t; }
        }
        #pragma unroll
        for (int t = O - 1; t >= 0; t--)
          if (bpd[t] == d) { bi = t; break; }
        int cls = (int)tl[bi] + 1;
        posBuf[b * 256 + rank] = d | (cls << 14) | (bi << 19);
      }
    }
  }
  __syncthreads();

  // ---- phase 4: radix top-k over sce (k = 3*npos), sum selected ----
  int k = npos * 3;
  if (k > D) k = D;
  unsigned prefix = 0; int kk = k;            // kk >= 3 (npos >= 1 via forced matches)
  for (int pass = 0; pass < 4; pass++) {
    int shift = 24 - 8 * pass;
    for (int i = tid; i < 16 * 256; i += 1024) ((int*)whist)[i] = 0;
    __syncthreads();
    unsigned himask = (pass == 0) ? 0u : (0xFFFFFFFFu << (shift + 8));
    for (int d = tid; d < D; d += 1024) {
      unsigned keyb = __float_as_uint(sce[d]);
      if ((keyb & himask) == (prefix & himask))
        atomicAdd(&whist[wav][(keyb >> shift) & 255], 1);
    }
    __syncthreads();
    if (tid < 256) {
      int h = 0;
      #pragma unroll
      for (int w = 0; w < 16; w++) h += whist[w][tid];
      hist[tid] = h;
    }
    __syncthreads();
    if (tid < 64) {
      int l = tid;
      int h0 = hist[l*4], h1 = hist[l*4+1], h2 = hist[l*4+2], h3 = hist[l*4+3];
      int loc4 = h0 + h1 + h2 + h3;
      int suf = loc4;
      #pragma unroll
      for (int s = 1; s < 64; s <<= 1) {
        int o = __shfl_down(suf, s, 64);
        if (l + s < 64) suf += o;
      }
      int snext = suf - loc4;
      int s3 = snext + h3, s2 = s3 + h2, s1 = s2 + h1, s0 = s1 + h0;
      if (s3 >= kk && snext < kk) { sh_prefix = prefix | ((unsigned)(l*4+3) << shift); sh_k = kk - snext; }
      if (s2 >= kk && s3 < kk)    { sh_prefix = prefix | ((unsigned)(l*4+2) << shift); sh_k = kk - s3; }
      if (s1 >= kk && s2 < kk)    { sh_prefix = prefix | ((unsigned)(l*4+1) << shift); sh_k = kk - s2; }
      if (s0 >= kk && s1 < kk)    { sh_prefix = prefix | ((unsigned)(l*4+0) << shift); sh_k = kk - s1; }
    }
    __syncthreads();
    prefix = sh_prefix; kk = sh_k;
    __syncthreads();
  }
  float T = __uint_as_float(prefix);
  double sgt = 0.0; int cgt = 0;
  for (int d = tid; d < D; d += 1024) {
    float v = sce[d];
    if (__float_as_uint(v) > prefix) { sgt += (double)v; cgt++; }
  }
  double wv = waveSumD(sgt);
  double wc = waveSumD((double)cgt);
  if (lane == 0) { wsum[wav] = wv; wcnt[wav] = wc; }
  __syncthreads();
  if (tid == 0) {
    double tsg = 0, tcg = 0;
    #pragma unroll
    for (int w = 0; w < 16; w++) { tsg += wsum[w]; tcg += wcnt[w]; }
    atomicAdd(&acc->ce_neg, tsg + ((double)k - tcg) * (double)T);
  }
}

// ============ K2: gather first-256 positives' embeddings ============
__global__ __launch_bounds__(256) void k_gath(
    const float* __restrict__ line, const float* __restrict__ targets,
    const int* __restrict__ posBuf, const int* __restrict__ posCnt,
    Accum* acc, float* __restrict__ emb, float* __restrict__ nemb,
    float* __restrict__ qp, int* __restrict__ lab)
{
  __shared__ int spre[B + 1];
  __shared__ int sPc;
  int g = threadIdx.x;
  if (g == 0) {
    int s = 0;
    for (int bb = 0; bb < B; bb++) { spre[bb] = s; s += posCnt[bb]; }
    spre[B] = s;
    sPc = (s < 256) ? s : 256;
    acc->Pc = sPc;
  }
  __syncthreads();
  int Pc = sPc;
  if (g >= Pc) return;       // rows >= Pc never contribute (masked in k_pt)
  int b = 0;
  #pragma unroll
  for (int bb = 1; bb < B; bb++) if (g >= spre[bb]) b = bb;
  int r = g - spre[b];
  int packed = posBuf[b * 256 + r];
  int d   = packed & 0x3FFF;
  int cls = (packed >> 14) & 31;
  int bi  = (packed >> 19) & 7;
  size_t flat = (size_t)b * D + d;
  const float4* e4 = (const float4*)(line + flat * L);
  float4* o4 = (float4*)(emb + g * L);
  float4* n4 = (float4*)(nemb + g * L);
  float4 v[8];
  float nrm2 = 0.f;
  #pragma unroll
  for (int c = 0; c < 8; c++) {
    v[c] = e4[c];
    o4[c] = v[c];
    nrm2 += v[c].x*v[c].x + v[c].y*v[c].y + v[c].z*v[c].z + v[c].w*v[c].w;
  }
  float inv = 1.f / fmaxf(sqrtf(nrm2), 1e-12f);
  #pragma unroll
  for (int c = 0; c < 8; c++) {
    float4 t = v[c];
    t.x *= inv; t.y *= inv; t.z *= inv; t.w *= inv;
    n4[c] = t;
  }
  lab[g] = cls;
  const float* tr = targets + ((size_t)b * O + bi) * 9;
  qp[g * 3 + 0] = tr[5]; qp[g * 3 + 1] = tr[6]; qp[g * 3 + 2] = tr[7];
}

// ============ K3: fused pairwise dist/masks/desk + triplet loop ============
// trip row i only needs dist row i + row-i masks -> no global dist round-trip.
__global__ __launch_bounds__(256) void k_pt(
    const float* __restrict__ emb, const float* __restrict__ nemb,
    const float* __restrict__ qp, const int* __restrict__ lab, Accum* acc)
{
  __shared__ float ei[L], ni[L], qi[3];
  __shared__ int li, sPc;
  __shared__ float sd[256];
  __shared__ unsigned long long spm[4], snm[4];
  __shared__ double w1[4], w2[4], w3[4];
  int i = blockIdx.x, j = threadIdx.x;
  int lane = j & 63, wave = j >> 6;
  if (j < L) { ei[j] = emb[i * L + j]; ni[j] = nemb[i * L + j]; }
  if (j < 3) qi[j] = qp[i * 3 + j];
  if (j == 0) { li = lab[i]; sPc = acc->Pc; }
  __syncthreads();
  int Pc = sPc;
  bool vi = (i < Pc), vj = (j < Pc);
  const float4* nj4 = (const float4*)(nemb + j * L);
  const float4* ej4 = (const float4*)(emb + j * L);
  float sq = 0.f, esq = 0.f;
  #pragma unroll
  for (int c = 0; c < 8; c++) {
    float4 nn = nj4[c], ee = ej4[c];
    float d0 = ni[c*4+0] - nn.x, d1 = ni[c*4+1] - nn.y, d2 = ni[c*4+2] - nn.z, d3 = ni[c*4+3] - nn.w;
    sq += d0*d0 + d1*d1 + d2*d2 + d3*d3;
    float e0 = ei[c*4+0] - ee.x, e1 = ei[c*4+1] - ee.y, e2 = ei[c*4+2] - ee.z, e3 = ei[c*4+3] - ee.w;
    esq += e0*e0 + e1*e1 + e2*e2 + e3*e3;
  }
  float dd = sqrtf(fmaxf(sq, 1e-12f));
  sd[j] = dd;
  float qsq = 0.f;
  #pragma unroll
  for (int c = 0; c < 3; c++) { float dq = qi[c] - qp[j * 3 + c]; qsq += dq * dq; }
  bool vp = vi && vj && (i != j);
  bool same = (li == lab[j]);
  bool pp = vp && same && (dd > 0.2f);
  bool np = vp && !same && (dd < 0.8f);
  unsigned long long pb = __ballot(pp), nb = __ballot(np);
  float diff = esq - qsq;
  double dsk = pp ? (double)diff * (double)diff : 0.0;
  double dw = waveSumD(dsk);
  if (lane == 0) {
    spm[wave] = pb; snm[wave] = nb; w1[wave] = dw;
    if (pb) atomicAdd(&acc->n_pp, (unsigned long long)__popcll(pb));
    if (nb) atomicAdd(&acc->n_np, (unsigned long long)__popcll(nb));
  }
  __syncthreads();
  if (j == 0) {
    double t = w1[0] + w1[1] + w1[2] + w1[3];
    if (t != 0.0) atomicAdd(&acc->desk, t);
  }
  // ---- triplet part on this row ----
  unsigned long long pm0 = spm[0], pm1 = spm[1], pm2 = spm[2], pm3 = spm[3];
  unsigned long long nm0 = snm[0], nm1 = snm[1], nm2 = snm[2], nm3 = snm[3];
  bool anyp = (pm0 | pm1 | pm2 | pm3) != 0ull;
  bool anyn = (nm0 | nm1 | nm2 | nm3) != 0ull;
  double s = 0.0, c = 0.0;
  if (anyp && anyn) {
    for (int idx = j; idx < 65536; idx += 256) {
      int jj = idx & 255, kx = idx >> 8;
      unsigned long long pmw = (jj < 64) ? pm0 : (jj < 128) ? pm1 : (jj < 192) ? pm2 : pm3;
      unsigned long long nmw = (kx < 64) ? nm0 : (kx < 128) ? nm1 : (kx < 192) ? nm2 : nm3;
      if (((pmw >> (jj & 63)) & 1ull) && ((nmw >> (kx & 63)) & 1ull)) {
        float x = sd[jj] - sd[kx] + 0.2f;
        if (x > 0.f) { s += (double)x; c += 1.0; }
      }
    }
  }
  double ws = waveSumD(s), wc = waveSumD(c);
  if (lane == 0) { w2[wave] = ws; w3[wave] = wc; }
  __syncthreads();
  if (j == 0) {
    double ts = w2[0] + w2[1] + w2[2] + w2[3];
    double tc = w3[0] + w3[1] + w3[2] + w3[3];
    if (ts != 0.0) atomicAdd(&acc->trip_sum, ts);
    if (tc != 0.0) atomicAdd(&acc->trip_cnt, tc);
  }
}

// ============ K4: finalize ============
__global__ void k_final(const Accum* acc, float* out) {
  double N = (acc->total_pos > 0) ? (double)acc->total_pos : 1.0;
  out[0] = (float)(acc->loss_l / N);
  out[1] = (float)((acc->ce_pos + acc->ce_neg) / N);
  out[2] = (float)(acc->loss_p / N);
  double cnt = (acc->trip_cnt > 0.0) ? acc->trip_cnt : 1.0;
  double loss_t = acc->trip_sum / cnt;
  double npp = (acc->n_pp > 0ull) ? (double)acc->n_pp : 1.0;
  unsigned long long tot = acc->n_pp + acc->n_np;
  double denom = (tot > 0ull) ? (double)tot : 1.0;
  double Ldesk = acc->desk / npp + loss_t / denom;
  Ldesk = Ldesk / npp / 32.0;
  out[3] = (float)Ldesk;
  out[4] = (float)loss_t;
}

extern "C" void kernel_launch(void* const* d_in, const int* in_sizes, int n_in,
                              void* d_out, int out_size, void* d_ws, size_t ws_size,
                              hipStream_t stream) {
  const float* loc     = (const float*)d_in[0];
  const float* conf    = (const float*)d_in[1];
  const float* line    = (const float*)d_in[2];
  const float* pose    = (const float*)d_in[3];
  const float* dbox    = (const float*)d_in[4];
  const float* targets = (const float*)d_in[5];
  float* out = (float*)d_out;

  char* ws = (char*)d_ws;
  size_t off = 0;
  auto alloc = [&](size_t bytes) -> char* {
    char* p = ws + off;
    off += (bytes + 255) & ~(size_t)255;
    return p;
  };
  Accum* acc    = (Accum*)alloc(sizeof(Accum));   // first 256 B: one small memset
  int* posBuf   = (int*)alloc(B * 256 * 4);
  int* posCnt   = (int*)alloc(B * 4);
  float* emb    = (float*)alloc(256 * L * 4);
  float* nemb   = (float*)alloc(256 * L * 4);
  float* qp     = (float*)alloc(256 * 3 * 4);
  int* lab      = (int*)alloc(256 * 4);

  hipMemsetAsync(acc, 0, 256, stream);
  k_fused <<<B,   1024, 0, stream>>>(loc, conf, pose, dbox, targets, posBuf, posCnt, acc);
  k_gath  <<<1,    256, 0, stream>>>(line, targets, posBuf, posCnt, acc, emb, nemb, qp, lab);
  k_pt    <<<256,  256, 0, stream>>>(emb, nemb, qp, lab, acc);
  k_final <<<1,      1, 0, stream>>>(acc, out);
}